// Round 1
// baseline (437.389 us; speedup 1.0000x reference)
//
#include <hip/hip_runtime.h>

// AttentionHead  B=4, T=2048, C=1024, HEAD=2048, fp32 in/out.
// Round 4: gemm_qk rebuilt as 256x256 8-phase pipelined GEMM (T2 st_16x32 LDS
// swizzle + T3/T4 counted vmcnt(4) + T5 setprio). m97-style 2-barrier core kept
// for gemm_v / gemm_s / gemm_o this round.

#define T_    2048
#define C_    1024
#define B_    4
#define NQK   4096
#define SCALE 0.03125f   // C^-0.5 = 1/32 exactly

typedef __attribute__((ext_vector_type(4))) float floatx4;
typedef __attribute__((ext_vector_type(8))) short short8;
typedef __attribute__((ext_vector_type(8))) unsigned short ushortx8;

__device__ __forceinline__ unsigned short f2bf(float f) {
  unsigned int u = __float_as_uint(f);
  unsigned int r = (u + 0x7fffu + ((u >> 16) & 1u)) >> 16;  // RNE
  return (unsigned short)r;
}

// ---------------------------------------------------------------- cast x
__global__ void cast_x_kernel(const float* __restrict__ x, ushort* __restrict__ xbf) {
  int i = blockIdx.x * 256 + threadIdx.x;          // over N/4 = 2097152
  float4 v = ((const float4*)x)[i];
  ushort4 o;
  o.x = f2bf(v.x); o.y = f2bf(v.y); o.z = f2bf(v.z); o.w = f2bf(v.w);
  ((ushort4*)xbf)[i] = o;
}

// ------------------------------------------- cast + transpose W -> WtT[n][k]
__global__ void wcast_t_kernel(const float* __restrict__ Wq, const float* __restrict__ Wk,
                               const float* __restrict__ Wv, ushort* __restrict__ WtT) {
  int k0 = blockIdx.x * 32;           // over C=1024
  int n0 = blockIdx.y * 32;           // over 6144
  const float* W = (n0 < 2048) ? Wq : (n0 < 4096 ? Wk : Wv);
  int nl0 = n0 & 2047;
  __shared__ ushort tile[32][33];
  int tx = threadIdx.x, ty = threadIdx.y;
  for (int r = ty; r < 32; r += 8)
    tile[r][tx] = f2bf(W[(size_t)(k0 + r) * 2048 + nl0 + tx]);
  __syncthreads();
  for (int r = ty; r < 32; r += 8)
    WtT[(size_t)(n0 + r) * 1024 + k0 + tx] = tile[tx][r];
}

// ---------------------------------------------------------------- bias concat
__global__ void bias_cat_kernel(const float* __restrict__ bq, const float* __restrict__ bk,
                                const float* __restrict__ bv, float* __restrict__ bcat) {
  int i = blockIdx.x * 256 + threadIdx.x;
  if (i < 6144) {
    const float* s = (i < 2048) ? bq : (i < 4096 ? bk : bv);
    bcat[i] = s[i & 2047];
  }
}

// ------------------------------------------------------- GEMM core (m97 BT)
__device__ __forceinline__ void stage128x32(const ushort* g, int ld, char* lds,
                                            int wave, int lane) {
#pragma unroll
  for (int c = 0; c < 2; ++c) {
    int chunk = wave + 4 * c;                       // 8 chunks of 16 rows
    const ushort* gaddr = g + (size_t)(chunk * 16 + (lane >> 2)) * ld + (lane & 3) * 8;
    char* laddr = lds + chunk * 1024;               // wave-uniform
    __builtin_amdgcn_global_load_lds((const __attribute__((address_space(1))) unsigned int*)gaddr,
                                     (__attribute__((address_space(3))) unsigned int*)laddr,
                                     16, 0, 0);
  }
}

__device__ __forceinline__ void gemm_core(const ushort* A, int lda,
                                          const ushort* Bm, int ldb, int ksteps,
                                          char* ldsA, char* ldsB, floatx4 acc[4][4]) {
  int tid = threadIdx.x;
  int wave = tid >> 6, lane = tid & 63;
  int wm = wave >> 1, wn = wave & 1;
  int koff2 = ((lane >> 4) * 8) * 2;   // byte offset of k-fragment
  int rbase = lane & 15;
  for (int s = 0; s < ksteps; ++s) {
    __syncthreads();                              // LDS reads of prev iter done
    stage128x32(A + s * 32, lda, ldsA, wave, lane);
    stage128x32(Bm + s * 32, ldb, ldsB, wave, lane);
    __syncthreads();                              // vmcnt drain before reads
    short8 af[4], bf[4];
#pragma unroll
    for (int i = 0; i < 4; ++i) {
      af[i] = *(const short8*)(ldsA + (wm * 64 + i * 16 + rbase) * 64 + koff2);
      bf[i] = *(const short8*)(ldsB + (wn * 64 + i * 16 + rbase) * 64 + koff2);
    }
#pragma unroll
    for (int i = 0; i < 4; ++i)
#pragma unroll
      for (int j = 0; j < 4; ++j)
        acc[i][j] = __builtin_amdgcn_mfma_f32_16x16x32_bf16(af[i], bf[j], acc[i][j], 0, 0, 0);
  }
}

// ===================== 256x256 8-phase GEMM (Q,K projection) =====================
// Geometry: BM=BN=256, BK=64, 8 waves (wm=wave>>2 in [0,2), wn=wave&3 in [0,4)),
// per-wave output 128x64 (acc[8][4] of 16x16 frags). LDS 128 KiB:
//   A: buf0 regions @0,16384; buf1 @32768,49152   (region = 128 rows x 64 cols bf16)
//   B: buf0 @65536,81920;     buf1 @98304,114688
// Swizzle (T2, m201): byte ^= ((byte>>9)&1)<<5, applied on ds_read address and
// inverted on the global SOURCE of global_load_lds (LDS dest stays linear).
// Stage schedule (race-free: a region is written only in phases strictly after
// its last barrier-confirmed read; reads per tile: ph1 A-lo+B-lo, ph2 B-hi,
// ph3 A-hi, ph4 none):
//   ph1:(t+1,A,r0)->buf1  ph2:(t+1,A,r1)  ph3:(t+2,B,r0)->buf0  ph4:(t+2,B,r1)
//   ph5:(t+2,A,r0)->buf0  ph6:(t+2,A,r1)  ph7:(t+3,B,r0)->buf1  ph8:(t+3,B,r1)
// vmcnt(4) at ph4/ph8 only (2 half-tiles allowed outstanding); tail iter vmcnt(0).

#define MFMA16(a, b, c) __builtin_amdgcn_mfma_f32_16x16x32_bf16((a), (b), (c), 0, 0, 0)

#define GLDS16(gsrc, ldst)                                                                       \
  __builtin_amdgcn_global_load_lds((const __attribute__((address_space(1))) unsigned int*)(gsrc), \
                                   (__attribute__((address_space(3))) unsigned int*)(ldst), 16, 0, 0)
#define STAGE2(gsrc, ldst) do { GLDS16((gsrc), (ldst)); GLDS16((gsrc) + 8192, (ldst) + 1024); } while (0)

#define PHASE_MID() do {                                   \
  __builtin_amdgcn_sched_barrier(0);                       \
  __builtin_amdgcn_s_barrier();                            \
  asm volatile("s_waitcnt lgkmcnt(0)" ::: "memory");       \
  __builtin_amdgcn_sched_barrier(0);                       \
  __builtin_amdgcn_s_setprio(1);                           \
} while (0)

#define PHASE_END() do {                                   \
  __builtin_amdgcn_s_setprio(0);                           \
  __builtin_amdgcn_sched_barrier(0);                       \
  __builtin_amdgcn_s_barrier();                            \
  __builtin_amdgcn_sched_barrier(0);                       \
} while (0)

template <bool TAIL>
__device__ __forceinline__ void iter_qk(const ushort* __restrict__ Ap,
                                        const ushort* __restrict__ Bp,
                                        char* lds, int kt0, int wave, int wm, int wn,
                                        int srcOff, int lnoffS, floatx4 (&acc)[8][4]) {
  char* rA0 = lds + wm * 16384;                    // tile kt0   (buf0) A, this wave
  char* rA1 = rA0 + 32768;                         // tile kt0+1 (buf1) A
  char* rB0 = lds + 65536 + (wn >> 1) * 16384 + (wn & 1) * 8192;
  char* rB1 = rB0 + 32768;
  const ushort* sA1 = Ap + (kt0 + 1) * 64 + srcOff;   // stage srcs (elem offsets)
  const ushort* sA2 = Ap + (kt0 + 2) * 64 + srcOff;
  const ushort* sB2 = Bp + (kt0 + 2) * 64 + srcOff;
  const ushort* sB3 = Bp + (kt0 + 3) * 64 + srcOff;
  short8 af[4][2], blo[2][2], bhi[2][2];

  // ---- phase 1: tile kt0, (m-lo, n-lo) --------------------------------
#pragma unroll
  for (int mi = 0; mi < 4; ++mi) {
    af[mi][0] = *(const short8*)(rA0 + mi * 2048 + lnoffS);
    af[mi][1] = *(const short8*)(rA0 + mi * 2048 + lnoffS + 64);
  }
#pragma unroll
  for (int nj = 0; nj < 2; ++nj) {
    blo[nj][0] = *(const short8*)(rB0 + nj * 2048 + lnoffS);
    blo[nj][1] = *(const short8*)(rB0 + nj * 2048 + lnoffS + 64);
  }
  STAGE2(sA1, lds + 32768 + wave * 2048);
  PHASE_MID();
#pragma unroll
  for (int mi = 0; mi < 4; ++mi)
#pragma unroll
    for (int nj = 0; nj < 2; ++nj) {
      acc[mi][nj] = MFMA16(af[mi][0], blo[nj][0], acc[mi][nj]);
      acc[mi][nj] = MFMA16(af[mi][1], blo[nj][1], acc[mi][nj]);
    }
  PHASE_END();

  // ---- phase 2: (m-lo, n-hi) ------------------------------------------
#pragma unroll
  for (int nj = 0; nj < 2; ++nj) {
    bhi[nj][0] = *(const short8*)(rB0 + (2 + nj) * 2048 + lnoffS);
    bhi[nj][1] = *(const short8*)(rB0 + (2 + nj) * 2048 + lnoffS + 64);
  }
  STAGE2(sA1 + 131072, lds + 49152 + wave * 2048);
  PHASE_MID();
#pragma unroll
  for (int mi = 0; mi < 4; ++mi)
#pragma unroll
    for (int nj = 0; nj < 2; ++nj) {
      acc[mi][2 + nj] = MFMA16(af[mi][0], bhi[nj][0], acc[mi][2 + nj]);
      acc[mi][2 + nj] = MFMA16(af[mi][1], bhi[nj][1], acc[mi][2 + nj]);
    }
  PHASE_END();

  // ---- phase 3: (m-hi, n-hi) ------------------------------------------
#pragma unroll
  for (int mi = 0; mi < 4; ++mi) {
    af[mi][0] = *(const short8*)(rA0 + (4 + mi) * 2048 + lnoffS);
    af[mi][1] = *(const short8*)(rA0 + (4 + mi) * 2048 + lnoffS + 64);
  }
  if constexpr (!TAIL) STAGE2(sB2, lds + 65536 + wave * 2048);
  PHASE_MID();
#pragma unroll
  for (int mi = 0; mi < 4; ++mi)
#pragma unroll
    for (int nj = 0; nj < 2; ++nj) {
      acc[4 + mi][2 + nj] = MFMA16(af[mi][0], bhi[nj][0], acc[4 + mi][2 + nj]);
      acc[4 + mi][2 + nj] = MFMA16(af[mi][1], bhi[nj][1], acc[4 + mi][2 + nj]);
    }
  PHASE_END();

  // ---- phase 4: (m-hi, n-lo); vmcnt gate for buf1 ---------------------
  if constexpr (!TAIL) STAGE2(sB2 + 131072, lds + 81920 + wave * 2048);
  PHASE_MID();
#pragma unroll
  for (int mi = 0; mi < 4; ++mi)
#pragma unroll
    for (int nj = 0; nj < 2; ++nj) {
      acc[4 + mi][nj] = MFMA16(af[mi][0], blo[nj][0], acc[4 + mi][nj]);
      acc[4 + mi][nj] = MFMA16(af[mi][1], blo[nj][1], acc[4 + mi][nj]);
    }
  __builtin_amdgcn_s_setprio(0);
  __builtin_amdgcn_sched_barrier(0);
  if constexpr (TAIL) asm volatile("s_waitcnt vmcnt(0)" ::: "memory");
  else                asm volatile("s_waitcnt vmcnt(4)" ::: "memory");
  __builtin_amdgcn_sched_barrier(0);
  __builtin_amdgcn_s_barrier();
  __builtin_amdgcn_sched_barrier(0);

  // ---- phase 5: tile kt0+1 (buf1), (m-lo, n-lo) -----------------------
#pragma unroll
  for (int mi = 0; mi < 4; ++mi) {
    af[mi][0] = *(const short8*)(rA1 + mi * 2048 + lnoffS);
    af[mi][1] = *(const short8*)(rA1 + mi * 2048 + lnoffS + 64);
  }
#pragma unroll
  for (int nj = 0; nj < 2; ++nj) {
    blo[nj][0] = *(const short8*)(rB1 + nj * 2048 + lnoffS);
    blo[nj][1] = *(const short8*)(rB1 + nj * 2048 + lnoffS + 64);
  }
  if constexpr (!TAIL) STAGE2(sA2, lds + wave * 2048);
  PHASE_MID();
#pragma unroll
  for (int mi = 0; mi < 4; ++mi)
#pragma unroll
    for (int nj = 0; nj < 2; ++nj) {
      acc[mi][nj] = MFMA16(af[mi][0], blo[nj][0], acc[mi][nj]);
      acc[mi][nj] = MFMA16(af[mi][1], blo[nj][1], acc[mi][nj]);
    }
  PHASE_END();

  // ---- phase 6: (m-lo, n-hi) ------------------------------------------
#pragma unroll
  for (int nj = 0; nj < 2; ++nj) {
    bhi[nj][0] = *(const short8*)(rB1 + (2 + nj) * 2048 + lnoffS);
    bhi[nj][1] = *(const short8*)(rB1 + (2 + nj) * 2048 + lnoffS + 64);
  }
  if constexpr (!TAIL) STAGE2(sA2 + 131072, lds + 16384 + wave * 2048);
  PHASE_MID();
#pragma unroll
  for (int mi = 0; mi < 4; ++mi)
#pragma unroll
    for (int nj = 0; nj < 2; ++nj) {
      acc[mi][2 + nj] = MFMA16(af[mi][0], bhi[nj][0], acc[mi][2 + nj]);
      acc[mi][2 + nj] = MFMA16(af[mi][1], bhi[nj][1], acc[mi][2 + nj]);
    }
  PHASE_END();

  // ---- phase 7: (m-hi, n-hi) ------------------------------------------
#pragma unroll
  for (int mi = 0; mi < 4; ++mi) {
    af[mi][0] = *(const short8*)(rA1 + (4 + mi) * 2048 + lnoffS);
    af[mi][1] = *(const short8*)(rA1 + (4 + mi) * 2048 + lnoffS + 64);
  }
  if constexpr (!TAIL) STAGE2(sB3, lds + 98304 + wave * 2048);
  PHASE_MID();
#pragma unroll
  for (int mi = 0; mi < 4; ++mi)
#pragma unroll
    for (int nj = 0; nj < 2; ++nj) {
      acc[4 + mi][2 + nj] = MFMA16(af[mi][0], bhi[nj][0], acc[4 + mi][2 + nj]);
      acc[4 + mi][2 + nj] = MFMA16(af[mi][1], bhi[nj][1], acc[4 + mi][2 + nj]);
    }
  PHASE_END();

  // ---- phase 8: (m-hi, n-lo); vmcnt gate for buf0 ---------------------
  if constexpr (!TAIL) STAGE2(sB3 + 131072, lds + 114688 + wave * 2048);
  PHASE_MID();
#pragma unroll
  for (int mi = 0; mi < 4; ++mi)
#pragma unroll
    for (int nj = 0; nj < 2; ++nj) {
      acc[4 + mi][nj] = MFMA16(af[mi][0], blo[nj][0], acc[4 + mi][nj]);
      acc[4 + mi][nj] = MFMA16(af[mi][1], blo[nj][1], acc[4 + mi][nj]);
    }
  __builtin_amdgcn_s_setprio(0);
  __builtin_amdgcn_sched_barrier(0);
  if constexpr (!TAIL) asm volatile("s_waitcnt vmcnt(4)" ::: "memory");
  __builtin_amdgcn_sched_barrier(0);
  __builtin_amdgcn_s_barrier();
  __builtin_amdgcn_sched_barrier(0);
}

__global__ __launch_bounds__(512) void gemm_qk256(const ushort* __restrict__ xbf,
                                                  const ushort* __restrict__ WtT,
                                                  const float* __restrict__ bcat,
                                                  ushort* __restrict__ QK) {
  __shared__ __align__(16) char lds[131072];
  int tm = blockIdx.x, tn = blockIdx.y;            // (32, 16)
  int tid = threadIdx.x;
  int wave = tid >> 6, ln = tid & 63;
  int wm = wave >> 2, wn = wave & 3;
  int ln15 = ln & 15;
  // ds_read byte offset with st_16x32 swizzle (bit9 of L == bit2 of row):
  int lnoffS = ln15 * 128 + (((ln >> 4) * 16) ^ ((ln15 & 4) << 3));
  // global source elem offset for linear-dest staging (inverse swizzle):
  int srcOff = (wave * 16 + (ln >> 3)) * 1024 + (((ln & 7) * 8) ^ ((ln >> 5) << 4));
  const ushort* Ap = xbf + (size_t)tm * 256 * 1024;
  const ushort* Bp = WtT + (size_t)tn * 256 * 1024;
  floatx4 acc[8][4];
#pragma unroll
  for (int i = 0; i < 8; ++i)
#pragma unroll
    for (int j = 0; j < 4; ++j) acc[i][j] = (floatx4){0.f, 0.f, 0.f, 0.f};

  // prologue: tile0 complete (buf0) + tile1 B halves (buf1)
  STAGE2(Ap + srcOff,                 lds + wave * 2048);
  STAGE2(Ap + 131072 + srcOff,        lds + 16384 + wave * 2048);
  STAGE2(Bp + srcOff,                 lds + 65536 + wave * 2048);
  STAGE2(Bp + 131072 + srcOff,        lds + 81920 + wave * 2048);
  STAGE2(Bp + 64 + srcOff,            lds + 98304 + wave * 2048);
  STAGE2(Bp + 64 + 131072 + srcOff,   lds + 114688 + wave * 2048);
  asm volatile("s_waitcnt vmcnt(4)" ::: "memory");
  __builtin_amdgcn_sched_barrier(0);
  __builtin_amdgcn_s_barrier();
  __builtin_amdgcn_sched_barrier(0);

#pragma unroll 1
  for (int i = 0; i < 7; ++i)
    iter_qk<false>(Ap, Bp, lds, 2 * i, wave, wm, wn, srcOff, lnoffS, acc);
  iter_qk<true>(Ap, Bp, lds, 14, wave, wm, wn, srcOff, lnoffS, acc);

  // epilogue: bias + bf16 store (C/D frag: col=lane&15, row=(lane>>4)*4+r)
  int colb = ln15, rowq = (ln >> 4) * 4;
#pragma unroll
  for (int nj = 0; nj < 4; ++nj) {
    int col = tn * 256 + wn * 64 + nj * 16 + colb;
    float bv = bcat[col];
#pragma unroll
    for (int mi = 0; mi < 8; ++mi) {
      int row = tm * 256 + wm * 128 + mi * 16 + rowq;
#pragma unroll
      for (int r = 0; r < 4; ++r)
        QK[(size_t)(row + r) * NQK + col] = f2bf(acc[mi][nj][r] + bv);
    }
  }
}

// --------------------------- GEMM: V projection, writes Vt[b][h][s] directly
__global__ __launch_bounds__(256) void gemm_v(const ushort* __restrict__ xbf,
                                              const ushort* __restrict__ WtT,
                                              const float* __restrict__ bcat,
                                              ushort* __restrict__ Vt) {
  __shared__ __align__(16) char lds[128 * 136 * 2];   // 34816 B; first 16KB = staging
  char* ldsA = lds;
  char* ldsB = lds + 8192;
  int tm = blockIdx.x, tn = blockIdx.y;          // tn in [0,16)
  floatx4 acc[4][4];
#pragma unroll
  for (int i = 0; i < 4; ++i)
#pragma unroll
    for (int j = 0; j < 4; ++j) acc[i][j] = (floatx4){0.f, 0.f, 0.f, 0.f};
  gemm_core(xbf + (size_t)tm * 128 * C_, C_, WtT + (size_t)(32 + tn) * 128 * C_, C_,
            C_ / 32, ldsA, ldsB, acc);
  int tid = threadIdx.x, wave = tid >> 6, lane = tid & 63;
  int wm = wave >> 1, wn = wave & 1;
  int colb = lane & 15, rowq = (lane >> 4) * 4;
  __syncthreads();                               // staging reads all consumed
  ushort* tileT = (ushort*)lds;                  // [h_local][s_local], stride 136
#pragma unroll
  for (int j = 0; j < 4; ++j) {
    int h = wn * 64 + j * 16 + colb;
    float bv = bcat[4096 + tn * 128 + h];
#pragma unroll
    for (int i = 0; i < 4; ++i) {
      int s = wm * 64 + i * 16 + rowq;
      ushort4 o4;
      o4.x = f2bf(acc[i][j][0] + bv);
      o4.y = f2bf(acc[i][j][1] + bv);
      o4.z = f2bf(acc[i][j][2] + bv);
      o4.w = f2bf(acc[i][j][3] + bv);
      *(ushort4*)(tileT + h * 136 + s) = o4;
    }
  }
  __syncthreads();
  int b = tm >> 4, sbase = (tm & 15) * 128;
  int hr = tid >> 4, sc = (tid & 15) * 8;
#pragma unroll
  for (int it = 0; it < 8; ++it) {
    int h = it * 16 + hr;
    ushortx8 v = *(const ushortx8*)(tileT + h * 136 + sc);
    *(ushortx8*)(Vt + ((size_t)b * T_ + tn * 128 + h) * T_ + sbase + sc) = v;
  }
}

// ------------------------------------------------- GEMM: S = Q*K^T (causal)
__global__ __launch_bounds__(256) void gemm_s(const ushort* __restrict__ QK,
                                              float* __restrict__ S) {
  int l = blockIdx.x, b = blockIdx.y;
  int tm = (int)((sqrtf(8.f * l + 1.f) - 1.f) * 0.5f);
  while ((tm + 1) * (tm + 2) / 2 <= l) ++tm;
  while (tm * (tm + 1) / 2 > l) --tm;
  int tn = l - tm * (tm + 1) / 2;
  __shared__ __align__(16) char ldsA[8192], ldsB[8192];
  floatx4 acc[4][4];
#pragma unroll
  for (int i = 0; i < 4; ++i)
#pragma unroll
    for (int j = 0; j < 4; ++j) acc[i][j] = (floatx4){0.f, 0.f, 0.f, 0.f};
  const ushort* Ab = QK + (size_t)b * T_ * NQK + (size_t)tm * 128 * NQK;         // Q rows
  const ushort* Bb = QK + (size_t)b * T_ * NQK + (size_t)tn * 128 * NQK + 2048;  // K rows
  gemm_core(Ab, NQK, Bb, NQK, T_ / 32, ldsA, ldsB, acc);
  float* Sb = S + (size_t)b * T_ * T_;
  int tid = threadIdx.x, wave = tid >> 6, lane = tid & 63;
  int wm = wave >> 1, wn = wave & 1;
  int colb = lane & 15, rowq = (lane >> 4) * 4;
#pragma unroll
  for (int i = 0; i < 4; ++i) {
    int row = tm * 128 + wm * 64 + i * 16 + rowq;
#pragma unroll
    for (int j = 0; j < 4; ++j) {
      int col = tn * 128 + wn * 64 + j * 16 + colb;
#pragma unroll
      for (int r = 0; r < 4; ++r)
        Sb[(size_t)(row + r) * T_ + col] = acc[i][j][r] * SCALE;
    }
  }
}

// ------------------------------------------------------------ causal softmax
__global__ __launch_bounds__(256) void softmax_causal(const float* __restrict__ S,
                                                      ushort* __restrict__ P) {
  int t = blockIdx.x, b = blockIdx.y;
  int tid = threadIdx.x;
  const float* srow = S + ((size_t)b * T_ + t) * T_;
  ushort* prow = P + ((size_t)b * T_ + t) * T_;
  int band = ((t >> 7) + 1) << 7;    // round_up(t+1, 128) == O-GEMM k_end
  float xv[8];
  float m = -INFINITY;
#pragma unroll
  for (int c = 0; c < 2; ++c) {
    int s0 = c * 1024 + tid * 4;
    float* xs = xv + c * 4;
    if (s0 < band) {
      float4 v = *(const float4*)(srow + s0);
      xs[0] = (s0 + 0 <= t) ? v.x : -INFINITY;  // scale applied in gemm_s
      xs[1] = (s0 + 1 <= t) ? v.y : -INFINITY;
      xs[2] = (s0 + 2 <= t) ? v.z : -INFINITY;
      xs[3] = (s0 + 3 <= t) ? v.w : -INFINITY;
      m = fmaxf(fmaxf(fmaxf(xs[0], xs[1]), fmaxf(xs[2], xs[3])), m);
    } else {
      xs[0] = xs[1] = xs[2] = xs[3] = -INFINITY;
    }
  }
  __shared__ float sm4[4];
  int wid = tid >> 6, ln = tid & 63;
#pragma unroll
  for (int o = 32; o; o >>= 1) m = fmaxf(m, __shfl_xor(m, o));
  if (ln == 0) sm4[wid] = m;
  __syncthreads();
  m = fmaxf(fmaxf(sm4[0], sm4[1]), fmaxf(sm4[2], sm4[3]));
  __syncthreads();
  float sum = 0.f;
#pragma unroll
  for (int k = 0; k < 8; ++k) { xv[k] = __expf(xv[k] - m); sum += xv[k]; }
#pragma unroll
  for (int o = 32; o; o >>= 1) sum += __shfl_xor(sum, o);
  if (ln == 0) sm4[wid] = sum;
  __syncthreads();
  sum = sm4[0] + sm4[1] + sm4[2] + sm4[3];
  float inv = 1.0f / sum;
#pragma unroll
  for (int c = 0; c < 2; ++c) {
    int s0 = c * 1024 + tid * 4;
    if (s0 < band) {
      ushort4 o4;
      o4.x = f2bf(xv[c * 4 + 0] * inv);
      o4.y = f2bf(xv[c * 4 + 1] * inv);
      o4.z = f2bf(xv[c * 4 + 2] * inv);
      o4.w = f2bf(xv[c * 4 + 3] * inv);
      *(ushort4*)(prow + s0) = o4;
    }
  }
}

// ------------------------------------------------ GEMM: O = P*V (k <= diag)
__global__ __launch_bounds__(256) void gemm_o(const ushort* __restrict__ P,
                                              const ushort* __restrict__ Vt,
                                              float* __restrict__ O) {
  int tn = blockIdx.x, tm = 15 - blockIdx.y, b = blockIdx.z;  // longest-first
  __shared__ __align__(16) char ldsA[8192], ldsB[8192];
  floatx4 acc[4][4];
#pragma unroll
  for (int i = 0; i < 4; ++i)
#pragma unroll
    for (int j = 0; j < 4; ++j) acc[i][j] = (floatx4){0.f, 0.f, 0.f, 0.f};
  const ushort* Ab = P + (size_t)b * T_ * T_ + (size_t)tm * 128 * T_;
  const ushort* Bb = Vt + (size_t)b * T_ * T_ + (size_t)tn * 128 * T_;
  gemm_core(Ab, T_, Bb, T_, (tm + 1) * 4, ldsA, ldsB, acc);  // k_end = (tm+1)*128
  float* Ob = O + (size_t)b * T_ * T_;
  int tid = threadIdx.x, wave = tid >> 6, lane = tid & 63;
  int wm = wave >> 1, wn = wave & 1;
  int colb = lane & 15, rowq = (lane >> 4) * 4;
#pragma unroll
  for (int i = 0; i < 4; ++i) {
    int row = tm * 128 + wm * 64 + i * 16 + rowq;
#pragma unroll
    for (int j = 0; j < 4; ++j) {
      int col = tn * 128 + wn * 64 + j * 16 + colb;
#pragma unroll
      for (int r = 0; r < 4; ++r)
        Ob[(size_t)(row + r) * T_ + col] = acc[i][j][r];
    }
  }
}

// ---------------------------------------------------------------- launcher
extern "C" void kernel_launch(void* const* d_in, const int* in_sizes, int n_in,
                              void* d_out, int out_size, void* d_ws, size_t ws_size,
                              hipStream_t stream) {
  (void)in_sizes; (void)n_in; (void)out_size; (void)ws_size;
  const float* x  = (const float*)d_in[0];
  const float* Wq = (const float*)d_in[1];
  const float* bq = (const float*)d_in[2];
  const float* Wk = (const float*)d_in[3];
  const float* bk = (const float*)d_in[4];
  const float* Wv = (const float*)d_in[5];
  const float* bv = (const float*)d_in[6];

  char* ws = (char*)d_ws;
  ushort* xbf  = (ushort*)(ws + 0);           // 16,777,216 B
  ushort* WtT  = (ushort*)(ws + 16777216);    // 12,582,912 B
  float*  bcat = (float*) (ws + 29360128);    //     24,576 B
  ushort* QK   = (ushort*)(ws + 29384704);    // 67,108,864 B  [8192][4096]
  ushort* P    = (ushort*)(ws + 96493568);    // 33,554,432 B
  ushort* Vt   = (ushort*)(ws + 130048000);   // 33,554,432 B  (end ~156 MiB)

  float* S = (float*)d_out;   // S scratch lives in d_out, later overwritten by O
  float* O = (float*)d_out;

  cast_x_kernel  <<<8192, 256, 0, stream>>>(x, xbf);
  wcast_t_kernel <<<dim3(32, 192), dim3(32, 8), 0, stream>>>(Wq, Wk, Wv, WtT);
  bias_cat_kernel<<<24, 256, 0, stream>>>(bq, bk, bv, bcat);
  gemm_qk256     <<<dim3(32, 16), 512, 0, stream>>>(xbf, WtT, bcat, QK);
  gemm_v         <<<dim3(64, 16), 256, 0, stream>>>(xbf, WtT, bcat, Vt);
  gemm_s         <<<dim3(136, 4), 256, 0, stream>>>(QK, S);
  softmax_causal <<<dim3(2048, 4), 256, 0, stream>>>(S, P);
  gemm_o         <<<dim3(16, 16, 4), 256, 0, stream>>>(P, Vt, O);
}

// Round 2
// 410.840 us; speedup vs baseline: 1.0646x; 1.0646x over previous
//
#include <hip/hip_runtime.h>

// AttentionHead  B=4, T=2048, C=1024, HEAD=2048, fp32 in/out.
// Round 5: fix the r4 8-phase gemm_qk256 regression.
//  (a) LDS swizzle was bit9->bit5 (32B) only: with 128B rows (= full bank
//      wrap) each ds_read_b128 touched only 2 of 8 bank-quads -> 8-way
//      conflict (6.3M). New swizzle: byte ^= (row&7)<<4 (G4 formula for
//      128B rows): rows fan across all 8 quads, 2 lanes/quad = free.
//      Second k-frag addressed via ^64 (swizzle carries bit 6 now);
//      global source pre-swizzle updated to match (involution).
//  (b) epilogue store reorder: nj innermost so each 128B line is written
//      by 4 consecutive stores (WRITE_SIZE was 2.25x ideal).

#define T_    2048
#define C_    1024
#define B_    4
#define NQK   4096
#define SCALE 0.03125f   // C^-0.5 = 1/32 exactly

typedef __attribute__((ext_vector_type(4))) float floatx4;
typedef __attribute__((ext_vector_type(8))) short short8;
typedef __attribute__((ext_vector_type(8))) unsigned short ushortx8;

__device__ __forceinline__ unsigned short f2bf(float f) {
  unsigned int u = __float_as_uint(f);
  unsigned int r = (u + 0x7fffu + ((u >> 16) & 1u)) >> 16;  // RNE
  return (unsigned short)r;
}

// ---------------------------------------------------------------- cast x
__global__ void cast_x_kernel(const float* __restrict__ x, ushort* __restrict__ xbf) {
  int i = blockIdx.x * 256 + threadIdx.x;          // over N/4 = 2097152
  float4 v = ((const float4*)x)[i];
  ushort4 o;
  o.x = f2bf(v.x); o.y = f2bf(v.y); o.z = f2bf(v.z); o.w = f2bf(v.w);
  ((ushort4*)xbf)[i] = o;
}

// ------------------------------------------- cast + transpose W -> WtT[n][k]
__global__ void wcast_t_kernel(const float* __restrict__ Wq, const float* __restrict__ Wk,
                               const float* __restrict__ Wv, ushort* __restrict__ WtT) {
  int k0 = blockIdx.x * 32;           // over C=1024
  int n0 = blockIdx.y * 32;           // over 6144
  const float* W = (n0 < 2048) ? Wq : (n0 < 4096 ? Wk : Wv);
  int nl0 = n0 & 2047;
  __shared__ ushort tile[32][33];
  int tx = threadIdx.x, ty = threadIdx.y;
  for (int r = ty; r < 32; r += 8)
    tile[r][tx] = f2bf(W[(size_t)(k0 + r) * 2048 + nl0 + tx]);
  __syncthreads();
  for (int r = ty; r < 32; r += 8)
    WtT[(size_t)(n0 + r) * 1024 + k0 + tx] = tile[tx][r];
}

// ---------------------------------------------------------------- bias concat
__global__ void bias_cat_kernel(const float* __restrict__ bq, const float* __restrict__ bk,
                                const float* __restrict__ bv, float* __restrict__ bcat) {
  int i = blockIdx.x * 256 + threadIdx.x;
  if (i < 6144) {
    const float* s = (i < 2048) ? bq : (i < 4096 ? bk : bv);
    bcat[i] = s[i & 2047];
  }
}

// ------------------------------------------------------- GEMM core (m97 BT)
__device__ __forceinline__ void stage128x32(const ushort* g, int ld, char* lds,
                                            int wave, int lane) {
#pragma unroll
  for (int c = 0; c < 2; ++c) {
    int chunk = wave + 4 * c;                       // 8 chunks of 16 rows
    const ushort* gaddr = g + (size_t)(chunk * 16 + (lane >> 2)) * ld + (lane & 3) * 8;
    char* laddr = lds + chunk * 1024;               // wave-uniform
    __builtin_amdgcn_global_load_lds((const __attribute__((address_space(1))) unsigned int*)gaddr,
                                     (__attribute__((address_space(3))) unsigned int*)laddr,
                                     16, 0, 0);
  }
}

__device__ __forceinline__ void gemm_core(const ushort* A, int lda,
                                          const ushort* Bm, int ldb, int ksteps,
                                          char* ldsA, char* ldsB, floatx4 acc[4][4]) {
  int tid = threadIdx.x;
  int wave = tid >> 6, lane = tid & 63;
  int wm = wave >> 1, wn = wave & 1;
  int koff2 = ((lane >> 4) * 8) * 2;   // byte offset of k-fragment
  int rbase = lane & 15;
  for (int s = 0; s < ksteps; ++s) {
    __syncthreads();                              // LDS reads of prev iter done
    stage128x32(A + s * 32, lda, ldsA, wave, lane);
    stage128x32(Bm + s * 32, ldb, ldsB, wave, lane);
    __syncthreads();                              // vmcnt drain before reads
    short8 af[4], bf[4];
#pragma unroll
    for (int i = 0; i < 4; ++i) {
      af[i] = *(const short8*)(ldsA + (wm * 64 + i * 16 + rbase) * 64 + koff2);
      bf[i] = *(const short8*)(ldsB + (wn * 64 + i * 16 + rbase) * 64 + koff2);
    }
#pragma unroll
    for (int i = 0; i < 4; ++i)
#pragma unroll
      for (int j = 0; j < 4; ++j)
        acc[i][j] = __builtin_amdgcn_mfma_f32_16x16x32_bf16(af[i], bf[j], acc[i][j], 0, 0, 0);
  }
}

// ===================== 256x256 8-phase GEMM (Q,K projection) =====================
// Geometry: BM=BN=256, BK=64, 8 waves (wm=wave>>2 in [0,2), wn=wave&3 in [0,4)),
// per-wave output 128x64 (acc[8][4] of 16x16 frags). LDS 128 KiB:
//   A: buf0 regions @0,16384; buf1 @32768,49152   (region = 128 rows x 64 cols bf16)
//   B: buf0 @65536,81920;     buf1 @98304,114688
// Swizzle: physical byte-in-row = logical ^ ((row&7)<<4). Rows are 128B (full
// 32-bank wrap) so only the k-offset picks banks; XORing row bits 0-2 into byte
// bits 4-6 fans the 16 rows of a fragment read across all 8 bank-quads
// (2 lanes/quad per quarter-wave = conflict-free). Applied on ds_read address;
// inverted on the global SOURCE of global_load_lds (LDS dest stays linear).
// Stage schedule (race-free: a region is written only in phases strictly after
// its last barrier-confirmed read; reads per tile: ph1 A-lo+B-lo, ph2 B-hi,
// ph3 A-hi, ph4 none):
//   ph1:(t+1,A,r0)->buf1  ph2:(t+1,A,r1)  ph3:(t+2,B,r0)->buf0  ph4:(t+2,B,r1)
//   ph5:(t+2,A,r0)->buf0  ph6:(t+2,A,r1)  ph7:(t+3,B,r0)->buf1  ph8:(t+3,B,r1)
// vmcnt(4) at ph4/ph8 only (2 half-tiles allowed outstanding); tail iter vmcnt(0).

#define MFMA16(a, b, c) __builtin_amdgcn_mfma_f32_16x16x32_bf16((a), (b), (c), 0, 0, 0)

#define GLDS16(gsrc, ldst)                                                                       \
  __builtin_amdgcn_global_load_lds((const __attribute__((address_space(1))) unsigned int*)(gsrc), \
                                   (__attribute__((address_space(3))) unsigned int*)(ldst), 16, 0, 0)
#define STAGE2(gsrc, ldst) do { GLDS16((gsrc), (ldst)); GLDS16((gsrc) + 8192, (ldst) + 1024); } while (0)

#define PHASE_MID() do {                                   \
  __builtin_amdgcn_sched_barrier(0);                       \
  __builtin_amdgcn_s_barrier();                            \
  asm volatile("s_waitcnt lgkmcnt(0)" ::: "memory");       \
  __builtin_amdgcn_sched_barrier(0);                       \
  __builtin_amdgcn_s_setprio(1);                           \
} while (0)

#define PHASE_END() do {                                   \
  __builtin_amdgcn_s_setprio(0);                           \
  __builtin_amdgcn_sched_barrier(0);                       \
  __builtin_amdgcn_s_barrier();                            \
  __builtin_amdgcn_sched_barrier(0);                       \
} while (0)

template <bool TAIL>
__device__ __forceinline__ void iter_qk(const ushort* __restrict__ Ap,
                                        const ushort* __restrict__ Bp,
                                        char* lds, int kt0, int wave, int wm, int wn,
                                        int srcOff, int lnoff0, floatx4 (&acc)[8][4]) {
  char* rA0 = lds + wm * 16384;                    // tile kt0   (buf0) A, this wave
  char* rA1 = rA0 + 32768;                         // tile kt0+1 (buf1) A
  char* rB0 = lds + 65536 + (wn >> 1) * 16384 + (wn & 1) * 8192;
  char* rB1 = rB0 + 32768;
  const ushort* sA1 = Ap + (kt0 + 1) * 64 + srcOff;   // stage srcs (elem offsets)
  const ushort* sA2 = Ap + (kt0 + 2) * 64 + srcOff;
  const ushort* sB2 = Bp + (kt0 + 2) * 64 + srcOff;
  const ushort* sB3 = Bp + (kt0 + 3) * 64 + srcOff;
  const int lnoff1 = lnoff0 ^ 64;                  // second k-frag (XOR: swz has bit6)
  short8 af[4][2], blo[2][2], bhi[2][2];

  // ---- phase 1: tile kt0, (m-lo, n-lo) --------------------------------
#pragma unroll
  for (int mi = 0; mi < 4; ++mi) {
    af[mi][0] = *(const short8*)(rA0 + mi * 2048 + lnoff0);
    af[mi][1] = *(const short8*)(rA0 + mi * 2048 + lnoff1);
  }
#pragma unroll
  for (int nj = 0; nj < 2; ++nj) {
    blo[nj][0] = *(const short8*)(rB0 + nj * 2048 + lnoff0);
    blo[nj][1] = *(const short8*)(rB0 + nj * 2048 + lnoff1);
  }
  STAGE2(sA1, lds + 32768 + wave * 2048);
  PHASE_MID();
#pragma unroll
  for (int mi = 0; mi < 4; ++mi)
#pragma unroll
    for (int nj = 0; nj < 2; ++nj) {
      acc[mi][nj] = MFMA16(af[mi][0], blo[nj][0], acc[mi][nj]);
      acc[mi][nj] = MFMA16(af[mi][1], blo[nj][1], acc[mi][nj]);
    }
  PHASE_END();

  // ---- phase 2: (m-lo, n-hi) ------------------------------------------
#pragma unroll
  for (int nj = 0; nj < 2; ++nj) {
    bhi[nj][0] = *(const short8*)(rB0 + (2 + nj) * 2048 + lnoff0);
    bhi[nj][1] = *(const short8*)(rB0 + (2 + nj) * 2048 + lnoff1);
  }
  STAGE2(sA1 + 131072, lds + 49152 + wave * 2048);
  PHASE_MID();
#pragma unroll
  for (int mi = 0; mi < 4; ++mi)
#pragma unroll
    for (int nj = 0; nj < 2; ++nj) {
      acc[mi][2 + nj] = MFMA16(af[mi][0], bhi[nj][0], acc[mi][2 + nj]);
      acc[mi][2 + nj] = MFMA16(af[mi][1], bhi[nj][1], acc[mi][2 + nj]);
    }
  PHASE_END();

  // ---- phase 3: (m-hi, n-hi) ------------------------------------------
#pragma unroll
  for (int mi = 0; mi < 4; ++mi) {
    af[mi][0] = *(const short8*)(rA0 + (4 + mi) * 2048 + lnoff0);
    af[mi][1] = *(const short8*)(rA0 + (4 + mi) * 2048 + lnoff1);
  }
  if constexpr (!TAIL) STAGE2(sB2, lds + 65536 + wave * 2048);
  PHASE_MID();
#pragma unroll
  for (int mi = 0; mi < 4; ++mi)
#pragma unroll
    for (int nj = 0; nj < 2; ++nj) {
      acc[4 + mi][2 + nj] = MFMA16(af[mi][0], bhi[nj][0], acc[4 + mi][2 + nj]);
      acc[4 + mi][2 + nj] = MFMA16(af[mi][1], bhi[nj][1], acc[4 + mi][2 + nj]);
    }
  PHASE_END();

  // ---- phase 4: (m-hi, n-lo); vmcnt gate for buf1 ---------------------
  if constexpr (!TAIL) STAGE2(sB2 + 131072, lds + 81920 + wave * 2048);
  PHASE_MID();
#pragma unroll
  for (int mi = 0; mi < 4; ++mi)
#pragma unroll
    for (int nj = 0; nj < 2; ++nj) {
      acc[4 + mi][nj] = MFMA16(af[mi][0], blo[nj][0], acc[4 + mi][nj]);
      acc[4 + mi][nj] = MFMA16(af[mi][1], blo[nj][1], acc[4 + mi][nj]);
    }
  __builtin_amdgcn_s_setprio(0);
  __builtin_amdgcn_sched_barrier(0);
  if constexpr (TAIL) asm volatile("s_waitcnt vmcnt(0)" ::: "memory");
  else                asm volatile("s_waitcnt vmcnt(4)" ::: "memory");
  __builtin_amdgcn_sched_barrier(0);
  __builtin_amdgcn_s_barrier();
  __builtin_amdgcn_sched_barrier(0);

  // ---- phase 5: tile kt0+1 (buf1), (m-lo, n-lo) -----------------------
#pragma unroll
  for (int mi = 0; mi < 4; ++mi) {
    af[mi][0] = *(const short8*)(rA1 + mi * 2048 + lnoff0);
    af[mi][1] = *(const short8*)(rA1 + mi * 2048 + lnoff1);
  }
#pragma unroll
  for (int nj = 0; nj < 2; ++nj) {
    blo[nj][0] = *(const short8*)(rB1 + nj * 2048 + lnoff0);
    blo[nj][1] = *(const short8*)(rB1 + nj * 2048 + lnoff1);
  }
  if constexpr (!TAIL) STAGE2(sA2, lds + wave * 2048);
  PHASE_MID();
#pragma unroll
  for (int mi = 0; mi < 4; ++mi)
#pragma unroll
    for (int nj = 0; nj < 2; ++nj) {
      acc[mi][nj] = MFMA16(af[mi][0], blo[nj][0], acc[mi][nj]);
      acc[mi][nj] = MFMA16(af[mi][1], blo[nj][1], acc[mi][nj]);
    }
  PHASE_END();

  // ---- phase 6: (m-lo, n-hi) ------------------------------------------
#pragma unroll
  for (int nj = 0; nj < 2; ++nj) {
    bhi[nj][0] = *(const short8*)(rB1 + (2 + nj) * 2048 + lnoff0);
    bhi[nj][1] = *(const short8*)(rB1 + (2 + nj) * 2048 + lnoff1);
  }
  if constexpr (!TAIL) STAGE2(sA2 + 131072, lds + 16384 + wave * 2048);
  PHASE_MID();
#pragma unroll
  for (int mi = 0; mi < 4; ++mi)
#pragma unroll
    for (int nj = 0; nj < 2; ++nj) {
      acc[mi][2 + nj] = MFMA16(af[mi][0], bhi[nj][0], acc[mi][2 + nj]);
      acc[mi][2 + nj] = MFMA16(af[mi][1], bhi[nj][1], acc[mi][2 + nj]);
    }
  PHASE_END();

  // ---- phase 7: (m-hi, n-hi) ------------------------------------------
#pragma unroll
  for (int mi = 0; mi < 4; ++mi) {
    af[mi][0] = *(const short8*)(rA1 + (4 + mi) * 2048 + lnoff0);
    af[mi][1] = *(const short8*)(rA1 + (4 + mi) * 2048 + lnoff1);
  }
  if constexpr (!TAIL) STAGE2(sB3, lds + 98304 + wave * 2048);
  PHASE_MID();
#pragma unroll
  for (int mi = 0; mi < 4; ++mi)
#pragma unroll
    for (int nj = 0; nj < 2; ++nj) {
      acc[4 + mi][2 + nj] = MFMA16(af[mi][0], bhi[nj][0], acc[4 + mi][2 + nj]);
      acc[4 + mi][2 + nj] = MFMA16(af[mi][1], bhi[nj][1], acc[4 + mi][2 + nj]);
    }
  PHASE_END();

  // ---- phase 8: (m-hi, n-lo); vmcnt gate for buf0 ---------------------
  if constexpr (!TAIL) STAGE2(sB3 + 131072, lds + 114688 + wave * 2048);
  PHASE_MID();
#pragma unroll
  for (int mi = 0; mi < 4; ++mi)
#pragma unroll
    for (int nj = 0; nj < 2; ++nj) {
      acc[4 + mi][nj] = MFMA16(af[mi][0], blo[nj][0], acc[4 + mi][nj]);
      acc[4 + mi][nj] = MFMA16(af[mi][1], blo[nj][1], acc[4 + mi][nj]);
    }
  __builtin_amdgcn_s_setprio(0);
  __builtin_amdgcn_sched_barrier(0);
  if constexpr (!TAIL) asm volatile("s_waitcnt vmcnt(4)" ::: "memory");
  __builtin_amdgcn_sched_barrier(0);
  __builtin_amdgcn_s_barrier();
  __builtin_amdgcn_sched_barrier(0);
}

__global__ __launch_bounds__(512) void gemm_qk256(const ushort* __restrict__ xbf,
                                                  const ushort* __restrict__ WtT,
                                                  const float* __restrict__ bcat,
                                                  ushort* __restrict__ QK) {
  __shared__ __align__(16) char lds[131072];
  int tm = blockIdx.x, tn = blockIdx.y;            // (32, 16)
  int tid = threadIdx.x;
  int wave = tid >> 6, ln = tid & 63;
  int wm = wave >> 2, wn = wave & 3;
  int ln15 = ln & 15;
  // ds_read byte offset, swizzle byte ^= (row&7)<<4 (row&7 == ln15&7):
  int lnoff0 = ln15 * 128 + (((ln >> 4) * 16) ^ ((ln15 & 7) << 4));
  // global source elem offset for linear-dest staging (inverse swizzle;
  // staging row&7 == ln>>3):
  int srcOff = (wave * 16 + (ln >> 3)) * 1024 + (((ln & 7) * 8) ^ ((ln >> 3) << 3));
  const ushort* Ap = xbf + (size_t)tm * 256 * 1024;
  const ushort* Bp = WtT + (size_t)tn * 256 * 1024;
  floatx4 acc[8][4];
#pragma unroll
  for (int i = 0; i < 8; ++i)
#pragma unroll
    for (int j = 0; j < 4; ++j) acc[i][j] = (floatx4){0.f, 0.f, 0.f, 0.f};

  // prologue: tile0 complete (buf0) + tile1 B halves (buf1)
  STAGE2(Ap + srcOff,                 lds + wave * 2048);
  STAGE2(Ap + 131072 + srcOff,        lds + 16384 + wave * 2048);
  STAGE2(Bp + srcOff,                 lds + 65536 + wave * 2048);
  STAGE2(Bp + 131072 + srcOff,        lds + 81920 + wave * 2048);
  STAGE2(Bp + 64 + srcOff,            lds + 98304 + wave * 2048);
  STAGE2(Bp + 64 + 131072 + srcOff,   lds + 114688 + wave * 2048);
  asm volatile("s_waitcnt vmcnt(4)" ::: "memory");
  __builtin_amdgcn_sched_barrier(0);
  __builtin_amdgcn_s_barrier();
  __builtin_amdgcn_sched_barrier(0);

#pragma unroll 1
  for (int i = 0; i < 7; ++i)
    iter_qk<false>(Ap, Bp, lds, 2 * i, wave, wm, wn, srcOff, lnoff0, acc);
  iter_qk<true>(Ap, Bp, lds, 14, wave, wm, wn, srcOff, lnoff0, acc);

  // epilogue: bias + bf16 store (C/D frag: col=lane&15, row=(lane>>4)*4+r).
  // nj innermost: 4 consecutive stores complete each 128B line.
  int colb = ln15, rowq = (ln >> 4) * 4;
  int colbase = tn * 256 + wn * 64 + colb;
  float bias[4];
#pragma unroll
  for (int nj = 0; nj < 4; ++nj) bias[nj] = bcat[colbase + nj * 16 - colb + colb];  // bcat[col]
#pragma unroll
  for (int nj = 0; nj < 4; ++nj) bias[nj] = bcat[tn * 256 + wn * 64 + nj * 16 + colb];
#pragma unroll
  for (int mi = 0; mi < 8; ++mi) {
    int row = tm * 256 + wm * 128 + mi * 16 + rowq;
#pragma unroll
    for (int r = 0; r < 4; ++r) {
      ushort* qrow = QK + (size_t)(row + r) * NQK;
#pragma unroll
      for (int nj = 0; nj < 4; ++nj)
        qrow[colbase + nj * 16] = f2bf(acc[mi][nj][r] + bias[nj]);
    }
  }
}

// --------------------------- GEMM: V projection, writes Vt[b][h][s] directly
__global__ __launch_bounds__(256) void gemm_v(const ushort* __restrict__ xbf,
                                              const ushort* __restrict__ WtT,
                                              const float* __restrict__ bcat,
                                              ushort* __restrict__ Vt) {
  __shared__ __align__(16) char lds[128 * 136 * 2];   // 34816 B; first 16KB = staging
  char* ldsA = lds;
  char* ldsB = lds + 8192;
  int tm = blockIdx.x, tn = blockIdx.y;          // tn in [0,16)
  floatx4 acc[4][4];
#pragma unroll
  for (int i = 0; i < 4; ++i)
#pragma unroll
    for (int j = 0; j < 4; ++j) acc[i][j] = (floatx4){0.f, 0.f, 0.f, 0.f};
  gemm_core(xbf + (size_t)tm * 128 * C_, C_, WtT + (size_t)(32 + tn) * 128 * C_, C_,
            C_ / 32, ldsA, ldsB, acc);
  int tid = threadIdx.x, wave = tid >> 6, lane = tid & 63;
  int wm = wave >> 1, wn = wave & 1;
  int colb = lane & 15, rowq = (lane >> 4) * 4;
  __syncthreads();                               // staging reads all consumed
  ushort* tileT = (ushort*)lds;                  // [h_local][s_local], stride 136
#pragma unroll
  for (int j = 0; j < 4; ++j) {
    int h = wn * 64 + j * 16 + colb;
    float bv = bcat[4096 + tn * 128 + h];
#pragma unroll
    for (int i = 0; i < 4; ++i) {
      int s = wm * 64 + i * 16 + rowq;
      ushort4 o4;
      o4.x = f2bf(acc[i][j][0] + bv);
      o4.y = f2bf(acc[i][j][1] + bv);
      o4.z = f2bf(acc[i][j][2] + bv);
      o4.w = f2bf(acc[i][j][3] + bv);
      *(ushort4*)(tileT + h * 136 + s) = o4;
    }
  }
  __syncthreads();
  int b = tm >> 4, sbase = (tm & 15) * 128;
  int hr = tid >> 4, sc = (tid & 15) * 8;
#pragma unroll
  for (int it = 0; it < 8; ++it) {
    int h = it * 16 + hr;
    ushortx8 v = *(const ushortx8*)(tileT + h * 136 + sc);
    *(ushortx8*)(Vt + ((size_t)b * T_ + tn * 128 + h) * T_ + sbase + sc) = v;
  }
}

// ------------------------------------------------- GEMM: S = Q*K^T (causal)
__global__ __launch_bounds__(256) void gemm_s(const ushort* __restrict__ QK,
                                              float* __restrict__ S) {
  int l = blockIdx.x, b = blockIdx.y;
  int tm = (int)((sqrtf(8.f * l + 1.f) - 1.f) * 0.5f);
  while ((tm + 1) * (tm + 2) / 2 <= l) ++tm;
  while (tm * (tm + 1) / 2 > l) --tm;
  int tn = l - tm * (tm + 1) / 2;
  __shared__ __align__(16) char ldsA[8192], ldsB[8192];
  floatx4 acc[4][4];
#pragma unroll
  for (int i = 0; i < 4; ++i)
#pragma unroll
    for (int j = 0; j < 4; ++j) acc[i][j] = (floatx4){0.f, 0.f, 0.f, 0.f};
  const ushort* Ab = QK + (size_t)b * T_ * NQK + (size_t)tm * 128 * NQK;         // Q rows
  const ushort* Bb = QK + (size_t)b * T_ * NQK + (size_t)tn * 128 * NQK + 2048;  // K rows
  gemm_core(Ab, NQK, Bb, NQK, T_ / 32, ldsA, ldsB, acc);
  float* Sb = S + (size_t)b * T_ * T_;
  int tid = threadIdx.x, wave = tid >> 6, lane = tid & 63;
  int wm = wave >> 1, wn = wave & 1;
  int colb = lane & 15, rowq = (lane >> 4) * 4;
#pragma unroll
  for (int i = 0; i < 4; ++i) {
    int row = tm * 128 + wm * 64 + i * 16 + rowq;
#pragma unroll
    for (int j = 0; j < 4; ++j) {
      int col = tn * 128 + wn * 64 + j * 16 + colb;
#pragma unroll
      for (int r = 0; r < 4; ++r)
        Sb[(size_t)(row + r) * T_ + col] = acc[i][j][r] * SCALE;
    }
  }
}

// ------------------------------------------------------------ causal softmax
__global__ __launch_bounds__(256) void softmax_causal(const float* __restrict__ S,
                                                      ushort* __restrict__ P) {
  int t = blockIdx.x, b = blockIdx.y;
  int tid = threadIdx.x;
  const float* srow = S + ((size_t)b * T_ + t) * T_;
  ushort* prow = P + ((size_t)b * T_ + t) * T_;
  int band = ((t >> 7) + 1) << 7;    // round_up(t+1, 128) == O-GEMM k_end
  float xv[8];
  float m = -INFINITY;
#pragma unroll
  for (int c = 0; c < 2; ++c) {
    int s0 = c * 1024 + tid * 4;
    float* xs = xv + c * 4;
    if (s0 < band) {
      float4 v = *(const float4*)(srow + s0);
      xs[0] = (s0 + 0 <= t) ? v.x : -INFINITY;  // scale applied in gemm_s
      xs[1] = (s0 + 1 <= t) ? v.y : -INFINITY;
      xs[2] = (s0 + 2 <= t) ? v.z : -INFINITY;
      xs[3] = (s0 + 3 <= t) ? v.w : -INFINITY;
      m = fmaxf(fmaxf(fmaxf(xs[0], xs[1]), fmaxf(xs[2], xs[3])), m);
    } else {
      xs[0] = xs[1] = xs[2] = xs[3] = -INFINITY;
    }
  }
  __shared__ float sm4[4];
  int wid = tid >> 6, ln = tid & 63;
#pragma unroll
  for (int o = 32; o; o >>= 1) m = fmaxf(m, __shfl_xor(m, o));
  if (ln == 0) sm4[wid] = m;
  __syncthreads();
  m = fmaxf(fmaxf(sm4[0], sm4[1]), fmaxf(sm4[2], sm4[3]));
  __syncthreads();
  float sum = 0.f;
#pragma unroll
  for (int k = 0; k < 8; ++k) { xv[k] = __expf(xv[k] - m); sum += xv[k]; }
#pragma unroll
  for (int o = 32; o; o >>= 1) sum += __shfl_xor(sum, o);
  if (ln == 0) sm4[wid] = sum;
  __syncthreads();
  sum = sm4[0] + sm4[1] + sm4[2] + sm4[3];
  float inv = 1.0f / sum;
#pragma unroll
  for (int c = 0; c < 2; ++c) {
    int s0 = c * 1024 + tid * 4;
    if (s0 < band) {
      ushort4 o4;
      o4.x = f2bf(xv[c * 4 + 0] * inv);
      o4.y = f2bf(xv[c * 4 + 1] * inv);
      o4.z = f2bf(xv[c * 4 + 2] * inv);
      o4.w = f2bf(xv[c * 4 + 3] * inv);
      *(ushort4*)(prow + s0) = o4;
    }
  }
}

// ------------------------------------------------ GEMM: O = P*V (k <= diag)
__global__ __launch_bounds__(256) void gemm_o(const ushort* __restrict__ P,
                                              const ushort* __restrict__ Vt,
                                              float* __restrict__ O) {
  int tn = blockIdx.x, tm = 15 - blockIdx.y, b = blockIdx.z;  // longest-first
  __shared__ __align__(16) char ldsA[8192], ldsB[8192];
  floatx4 acc[4][4];
#pragma unroll
  for (int i = 0; i < 4; ++i)
#pragma unroll
    for (int j = 0; j < 4; ++j) acc[i][j] = (floatx4){0.f, 0.f, 0.f, 0.f};
  const ushort* Ab = P + (size_t)b * T_ * T_ + (size_t)tm * 128 * T_;
  const ushort* Bb = Vt + (size_t)b * T_ * T_ + (size_t)tn * 128 * T_;
  gemm_core(Ab, T_, Bb, T_, (tm + 1) * 4, ldsA, ldsB, acc);  // k_end = (tm+1)*128
  float* Ob = O + (size_t)b * T_ * T_;
  int tid = threadIdx.x, wave = tid >> 6, lane = tid & 63;
  int wm = wave >> 1, wn = wave & 1;
  int colb = lane & 15, rowq = (lane >> 4) * 4;
#pragma unroll
  for (int i = 0; i < 4; ++i) {
    int row = tm * 128 + wm * 64 + i * 16 + rowq;
#pragma unroll
    for (int j = 0; j < 4; ++j) {
      int col = tn * 128 + wn * 64 + j * 16 + colb;
#pragma unroll
      for (int r = 0; r < 4; ++r)
        Ob[(size_t)(row + r) * T_ + col] = acc[i][j][r];
    }
  }
}

// ---------------------------------------------------------------- launcher
extern "C" void kernel_launch(void* const* d_in, const int* in_sizes, int n_in,
                              void* d_out, int out_size, void* d_ws, size_t ws_size,
                              hipStream_t stream) {
  (void)in_sizes; (void)n_in; (void)out_size; (void)ws_size;
  const float* x  = (const float*)d_in[0];
  const float* Wq = (const float*)d_in[1];
  const float* bq = (const float*)d_in[2];
  const float* Wk = (const float*)d_in[3];
  const float* bk = (const float*)d_in[4];
  const float* Wv = (const float*)d_in[5];
  const float* bv = (const float*)d_in[6];

  char* ws = (char*)d_ws;
  ushort* xbf  = (ushort*)(ws + 0);           // 16,777,216 B
  ushort* WtT  = (ushort*)(ws + 16777216);    // 12,582,912 B
  float*  bcat = (float*) (ws + 29360128);    //     24,576 B
  ushort* QK   = (ushort*)(ws + 29384704);    // 67,108,864 B  [8192][4096]
  ushort* P    = (ushort*)(ws + 96493568);    // 33,554,432 B
  ushort* Vt   = (ushort*)(ws + 130048000);   // 33,554,432 B  (end ~156 MiB)

  float* S = (float*)d_out;   // S scratch lives in d_out, later overwritten by O
  float* O = (float*)d_out;

  cast_x_kernel  <<<8192, 256, 0, stream>>>(x, xbf);
  wcast_t_kernel <<<dim3(32, 192), dim3(32, 8), 0, stream>>>(Wq, Wk, Wv, WtT);
  bias_cat_kernel<<<24, 256, 0, stream>>>(bq, bk, bv, bcat);
  gemm_qk256     <<<dim3(32, 16), 512, 0, stream>>>(xbf, WtT, bcat, QK);
  gemm_v         <<<dim3(64, 16), 256, 0, stream>>>(xbf, WtT, bcat, Vt);
  gemm_s         <<<dim3(136, 4), 256, 0, stream>>>(QK, S);
  softmax_causal <<<dim3(2048, 4), 256, 0, stream>>>(S, P);
  gemm_o         <<<dim3(16, 16, 4), 256, 0, stream>>>(P, Vt, O);
}

// Round 3
// 359.987 us; speedup vs baseline: 1.2150x; 1.1413x over previous
//
#include <hip/hip_runtime.h>

// AttentionHead  B=4, T=2048, C=1024, HEAD=2048, fp32 in/out.
// Round 6: port the validated 256x256 8-phase pipelined GEMM (r5 swizzle
// (row&7)<<4, counted vmcnt(4), setprio) to gemm_s and gemm_o. Softmax band
// widened to 256-granularity to match gemm_o256's k_end. gemm_v keeps the
// m97 core (transposed epilogue) this round.

#define T_    2048
#define C_    1024
#define B_    4
#define NQK   4096
#define SCALE 0.03125f   // C^-0.5 = 1/32 exactly

typedef __attribute__((ext_vector_type(4))) float floatx4;
typedef __attribute__((ext_vector_type(8))) short short8;
typedef __attribute__((ext_vector_type(8))) unsigned short ushortx8;

__device__ __forceinline__ unsigned short f2bf(float f) {
  unsigned int u = __float_as_uint(f);
  unsigned int r = (u + 0x7fffu + ((u >> 16) & 1u)) >> 16;  // RNE
  return (unsigned short)r;
}

// ---------------------------------------------------------------- cast x
__global__ void cast_x_kernel(const float* __restrict__ x, ushort* __restrict__ xbf) {
  int i = blockIdx.x * 256 + threadIdx.x;          // over N/4 = 2097152
  float4 v = ((const float4*)x)[i];
  ushort4 o;
  o.x = f2bf(v.x); o.y = f2bf(v.y); o.z = f2bf(v.z); o.w = f2bf(v.w);
  ((ushort4*)xbf)[i] = o;
}

// ------------------------------------------- cast + transpose W -> WtT[n][k]
__global__ void wcast_t_kernel(const float* __restrict__ Wq, const float* __restrict__ Wk,
                               const float* __restrict__ Wv, ushort* __restrict__ WtT) {
  int k0 = blockIdx.x * 32;           // over C=1024
  int n0 = blockIdx.y * 32;           // over 6144
  const float* W = (n0 < 2048) ? Wq : (n0 < 4096 ? Wk : Wv);
  int nl0 = n0 & 2047;
  __shared__ ushort tile[32][33];
  int tx = threadIdx.x, ty = threadIdx.y;
  for (int r = ty; r < 32; r += 8)
    tile[r][tx] = f2bf(W[(size_t)(k0 + r) * 2048 + nl0 + tx]);
  __syncthreads();
  for (int r = ty; r < 32; r += 8)
    WtT[(size_t)(n0 + r) * 1024 + k0 + tx] = tile[tx][r];
}

// ---------------------------------------------------------------- bias concat
__global__ void bias_cat_kernel(const float* __restrict__ bq, const float* __restrict__ bk,
                                const float* __restrict__ bv, float* __restrict__ bcat) {
  int i = blockIdx.x * 256 + threadIdx.x;
  if (i < 6144) {
    const float* s = (i < 2048) ? bq : (i < 4096 ? bk : bv);
    bcat[i] = s[i & 2047];
  }
}

// ------------------------------------------------------- GEMM core (m97 BT)
__device__ __forceinline__ void stage128x32(const ushort* g, int ld, char* lds,
                                            int wave, int lane) {
#pragma unroll
  for (int c = 0; c < 2; ++c) {
    int chunk = wave + 4 * c;                       // 8 chunks of 16 rows
    const ushort* gaddr = g + (size_t)(chunk * 16 + (lane >> 2)) * ld + (lane & 3) * 8;
    char* laddr = lds + chunk * 1024;               // wave-uniform
    __builtin_amdgcn_global_load_lds((const __attribute__((address_space(1))) unsigned int*)gaddr,
                                     (__attribute__((address_space(3))) unsigned int*)laddr,
                                     16, 0, 0);
  }
}

__device__ __forceinline__ void gemm_core(const ushort* A, int lda,
                                          const ushort* Bm, int ldb, int ksteps,
                                          char* ldsA, char* ldsB, floatx4 acc[4][4]) {
  int tid = threadIdx.x;
  int wave = tid >> 6, lane = tid & 63;
  int wm = wave >> 1, wn = wave & 1;
  int koff2 = ((lane >> 4) * 8) * 2;   // byte offset of k-fragment
  int rbase = lane & 15;
  for (int s = 0; s < ksteps; ++s) {
    __syncthreads();                              // LDS reads of prev iter done
    stage128x32(A + s * 32, lda, ldsA, wave, lane);
    stage128x32(Bm + s * 32, ldb, ldsB, wave, lane);
    __syncthreads();                              // vmcnt drain before reads
    short8 af[4], bf[4];
#pragma unroll
    for (int i = 0; i < 4; ++i) {
      af[i] = *(const short8*)(ldsA + (wm * 64 + i * 16 + rbase) * 64 + koff2);
      bf[i] = *(const short8*)(ldsB + (wn * 64 + i * 16 + rbase) * 64 + koff2);
    }
#pragma unroll
    for (int i = 0; i < 4; ++i)
#pragma unroll
      for (int j = 0; j < 4; ++j)
        acc[i][j] = __builtin_amdgcn_mfma_f32_16x16x32_bf16(af[i], bf[j], acc[i][j], 0, 0, 0);
  }
}

// ===================== 256x256 8-phase GEMM core (BT, bf16) =====================
// Geometry: BM=BN=256, BK=64, 8 waves (wm=wave>>2, wn=wave&3), per-wave output
// 128x64 (acc[8][4] of 16x16 frags). LDS 128 KiB:
//   A: buf0 @0,16384; buf1 @32768,49152   (region = 128 rows x 64 cols bf16)
//   B: buf0 @65536,81920; buf1 @98304,114688
// Swizzle: physical byte-in-row = logical ^ ((row&7)<<4). Rows are 128B (full
// 32-bank wrap); XORing row bits 0-2 into byte bits 4-6 fans fragment rows
// across all 8 bank-quads (2 lanes/quad per quarter-wave = conflict-free).
// Applied on ds_read; inverted on the global SOURCE of global_load_lds.
// Stage schedule per iter (tiles t=buf0, t+1=buf1):
//   ph1/2:(t+1,A)->buf1A  ph3/4:(t+2,B)->buf0B  ph5/6:(t+2,A)->buf0A
//   ph7/8:(t+3,B)->buf1B;  vmcnt(4) at ph4/ph8 only; tail iter vmcnt(0) at ph4.

#define MFMA16(a, b, c) __builtin_amdgcn_mfma_f32_16x16x32_bf16((a), (b), (c), 0, 0, 0)

#define GLDS16(gsrc, ldst)                                                                       \
  __builtin_amdgcn_global_load_lds((const __attribute__((address_space(1))) unsigned int*)(gsrc), \
                                   (__attribute__((address_space(3))) unsigned int*)(ldst), 16, 0, 0)

template <int LD>
__device__ __forceinline__ void stage_half(const ushort* gsrc, char* ldst) {
  GLDS16(gsrc, ldst);
  GLDS16(gsrc + 8 * LD, ldst + 1024);
}

#define PHASE_MID() do {                                   \
  __builtin_amdgcn_sched_barrier(0);                       \
  __builtin_amdgcn_s_barrier();                            \
  asm volatile("s_waitcnt lgkmcnt(0)" ::: "memory");       \
  __builtin_amdgcn_sched_barrier(0);                       \
  __builtin_amdgcn_s_setprio(1);                           \
} while (0)

#define PHASE_END() do {                                   \
  __builtin_amdgcn_s_setprio(0);                           \
  __builtin_amdgcn_sched_barrier(0);                       \
  __builtin_amdgcn_s_barrier();                            \
  __builtin_amdgcn_sched_barrier(0);                       \
} while (0)

template <int LDA, int LDB>
__device__ __forceinline__ void prologue256(const ushort* Ap, const ushort* Bp,
                                            char* lds, int wave, int srcOffA, int srcOffB) {
  stage_half<LDA>(Ap + srcOffA,                     lds + wave * 2048);
  stage_half<LDA>(Ap + 128 * LDA + srcOffA,         lds + 16384 + wave * 2048);
  stage_half<LDB>(Bp + srcOffB,                     lds + 65536 + wave * 2048);
  stage_half<LDB>(Bp + 128 * LDB + srcOffB,         lds + 81920 + wave * 2048);
  stage_half<LDB>(Bp + 64 + srcOffB,                lds + 98304 + wave * 2048);
  stage_half<LDB>(Bp + 64 + 128 * LDB + srcOffB,    lds + 114688 + wave * 2048);
  asm volatile("s_waitcnt vmcnt(4)" ::: "memory");
  __builtin_amdgcn_sched_barrier(0);
  __builtin_amdgcn_s_barrier();
  __builtin_amdgcn_sched_barrier(0);
}

template <int LDA, int LDB, bool TAIL>
__device__ __forceinline__ void iter256(const ushort* __restrict__ Ap,
                                        const ushort* __restrict__ Bp,
                                        char* lds, int kt0, int wave, int wm, int wn,
                                        int srcOffA, int srcOffB, int lnoff0,
                                        floatx4 (&acc)[8][4]) {
  char* rA0 = lds + wm * 16384;                    // tile kt0   (buf0) A, this wave
  char* rA1 = rA0 + 32768;                         // tile kt0+1 (buf1) A
  char* rB0 = lds + 65536 + (wn >> 1) * 16384 + (wn & 1) * 8192;
  char* rB1 = rB0 + 32768;
  const ushort* sA1 = Ap + (kt0 + 1) * 64 + srcOffA;
  const ushort* sA2 = Ap + (kt0 + 2) * 64 + srcOffA;
  const ushort* sB2 = Bp + (kt0 + 2) * 64 + srcOffB;
  const ushort* sB3 = Bp + (kt0 + 3) * 64 + srcOffB;
  const int lnoff1 = lnoff0 ^ 64;                  // second k-frag (swz carries bit6)
  short8 af[4][2], blo[2][2], bhi[2][2];

  // ---- phase 1: tile kt0, (m-lo, n-lo) --------------------------------
#pragma unroll
  for (int mi = 0; mi < 4; ++mi) {
    af[mi][0] = *(const short8*)(rA0 + mi * 2048 + lnoff0);
    af[mi][1] = *(const short8*)(rA0 + mi * 2048 + lnoff1);
  }
#pragma unroll
  for (int nj = 0; nj < 2; ++nj) {
    blo[nj][0] = *(const short8*)(rB0 + nj * 2048 + lnoff0);
    blo[nj][1] = *(const short8*)(rB0 + nj * 2048 + lnoff1);
  }
  stage_half<LDA>(sA1, lds + 32768 + wave * 2048);
  PHASE_MID();
#pragma unroll
  for (int mi = 0; mi < 4; ++mi)
#pragma unroll
    for (int nj = 0; nj < 2; ++nj) {
      acc[mi][nj] = MFMA16(af[mi][0], blo[nj][0], acc[mi][nj]);
      acc[mi][nj] = MFMA16(af[mi][1], blo[nj][1], acc[mi][nj]);
    }
  PHASE_END();

  // ---- phase 2: (m-lo, n-hi) ------------------------------------------
#pragma unroll
  for (int nj = 0; nj < 2; ++nj) {
    bhi[nj][0] = *(const short8*)(rB0 + (2 + nj) * 2048 + lnoff0);
    bhi[nj][1] = *(const short8*)(rB0 + (2 + nj) * 2048 + lnoff1);
  }
  stage_half<LDA>(sA1 + 128 * LDA, lds + 49152 + wave * 2048);
  PHASE_MID();
#pragma unroll
  for (int mi = 0; mi < 4; ++mi)
#pragma unroll
    for (int nj = 0; nj < 2; ++nj) {
      acc[mi][2 + nj] = MFMA16(af[mi][0], bhi[nj][0], acc[mi][2 + nj]);
      acc[mi][2 + nj] = MFMA16(af[mi][1], bhi[nj][1], acc[mi][2 + nj]);
    }
  PHASE_END();

  // ---- phase 3: (m-hi, n-hi) ------------------------------------------
#pragma unroll
  for (int mi = 0; mi < 4; ++mi) {
    af[mi][0] = *(const short8*)(rA0 + (4 + mi) * 2048 + lnoff0);
    af[mi][1] = *(const short8*)(rA0 + (4 + mi) * 2048 + lnoff1);
  }
  if constexpr (!TAIL) stage_half<LDB>(sB2, lds + 65536 + wave * 2048);
  PHASE_MID();
#pragma unroll
  for (int mi = 0; mi < 4; ++mi)
#pragma unroll
    for (int nj = 0; nj < 2; ++nj) {
      acc[4 + mi][2 + nj] = MFMA16(af[mi][0], bhi[nj][0], acc[4 + mi][2 + nj]);
      acc[4 + mi][2 + nj] = MFMA16(af[mi][1], bhi[nj][1], acc[4 + mi][2 + nj]);
    }
  PHASE_END();

  // ---- phase 4: (m-hi, n-lo); vmcnt gate for buf1 ---------------------
  if constexpr (!TAIL) stage_half<LDB>(sB2 + 128 * LDB, lds + 81920 + wave * 2048);
  PHASE_MID();
#pragma unroll
  for (int mi = 0; mi < 4; ++mi)
#pragma unroll
    for (int nj = 0; nj < 2; ++nj) {
      acc[4 + mi][nj] = MFMA16(af[mi][0], blo[nj][0], acc[4 + mi][nj]);
      acc[4 + mi][nj] = MFMA16(af[mi][1], blo[nj][1], acc[4 + mi][nj]);
    }
  __builtin_amdgcn_s_setprio(0);
  __builtin_amdgcn_sched_barrier(0);
  if constexpr (TAIL) asm volatile("s_waitcnt vmcnt(0)" ::: "memory");
  else                asm volatile("s_waitcnt vmcnt(4)" ::: "memory");
  __builtin_amdgcn_sched_barrier(0);
  __builtin_amdgcn_s_barrier();
  __builtin_amdgcn_sched_barrier(0);

  // ---- phase 5: tile kt0+1 (buf1), (m-lo, n-lo) -----------------------
#pragma unroll
  for (int mi = 0; mi < 4; ++mi) {
    af[mi][0] = *(const short8*)(rA1 + mi * 2048 + lnoff0);
    af[mi][1] = *(const short8*)(rA1 + mi * 2048 + lnoff1);
  }
#pragma unroll
  for (int nj = 0; nj < 2; ++nj) {
    blo[nj][0] = *(const short8*)(rB1 + nj * 2048 + lnoff0);
    blo[nj][1] = *(const short8*)(rB1 + nj * 2048 + lnoff1);
  }
  if constexpr (!TAIL) stage_half<LDA>(sA2, lds + wave * 2048);
  PHASE_MID();
#pragma unroll
  for (int mi = 0; mi < 4; ++mi)
#pragma unroll
    for (int nj = 0; nj < 2; ++nj) {
      acc[mi][nj] = MFMA16(af[mi][0], blo[nj][0], acc[mi][nj]);
      acc[mi][nj] = MFMA16(af[mi][1], blo[nj][1], acc[mi][nj]);
    }
  PHASE_END();

  // ---- phase 6: (m-lo, n-hi) ------------------------------------------
#pragma unroll
  for (int nj = 0; nj < 2; ++nj) {
    bhi[nj][0] = *(const short8*)(rB1 + (2 + nj) * 2048 + lnoff0);
    bhi[nj][1] = *(const short8*)(rB1 + (2 + nj) * 2048 + lnoff1);
  }
  if constexpr (!TAIL) stage_half<LDA>(sA2 + 128 * LDA, lds + 16384 + wave * 2048);
  PHASE_MID();
#pragma unroll
  for (int mi = 0; mi < 4; ++mi)
#pragma unroll
    for (int nj = 0; nj < 2; ++nj) {
      acc[mi][2 + nj] = MFMA16(af[mi][0], bhi[nj][0], acc[mi][2 + nj]);
      acc[mi][2 + nj] = MFMA16(af[mi][1], bhi[nj][1], acc[mi][2 + nj]);
    }
  PHASE_END();

  // ---- phase 7: (m-hi, n-hi) ------------------------------------------
#pragma unroll
  for (int mi = 0; mi < 4; ++mi) {
    af[mi][0] = *(const short8*)(rA1 + (4 + mi) * 2048 + lnoff0);
    af[mi][1] = *(const short8*)(rA1 + (4 + mi) * 2048 + lnoff1);
  }
  if constexpr (!TAIL) stage_half<LDB>(sB3, lds + 98304 + wave * 2048);
  PHASE_MID();
#pragma unroll
  for (int mi = 0; mi < 4; ++mi)
#pragma unroll
    for (int nj = 0; nj < 2; ++nj) {
      acc[4 + mi][2 + nj] = MFMA16(af[mi][0], bhi[nj][0], acc[4 + mi][2 + nj]);
      acc[4 + mi][2 + nj] = MFMA16(af[mi][1], bhi[nj][1], acc[4 + mi][2 + nj]);
    }
  PHASE_END();

  // ---- phase 8: (m-hi, n-lo); vmcnt gate for buf0 ---------------------
  if constexpr (!TAIL) stage_half<LDB>(sB3 + 128 * LDB, lds + 114688 + wave * 2048);
  PHASE_MID();
#pragma unroll
  for (int mi = 0; mi < 4; ++mi)
#pragma unroll
    for (int nj = 0; nj < 2; ++nj) {
      acc[4 + mi][nj] = MFMA16(af[mi][0], blo[nj][0], acc[4 + mi][nj]);
      acc[4 + mi][nj] = MFMA16(af[mi][1], blo[nj][1], acc[4 + mi][nj]);
    }
  __builtin_amdgcn_s_setprio(0);
  __builtin_amdgcn_sched_barrier(0);
  if constexpr (!TAIL) asm volatile("s_waitcnt vmcnt(4)" ::: "memory");
  __builtin_amdgcn_sched_barrier(0);
  __builtin_amdgcn_s_barrier();
  __builtin_amdgcn_sched_barrier(0);
}

// Per-thread addressing for the 256x256 core.
struct Addr256 {
  int wave, wm, wn, ln, ln15, lnoff0;
};
__device__ __forceinline__ Addr256 addr256() {
  Addr256 a;
  int tid = threadIdx.x;
  a.wave = tid >> 6; a.ln = tid & 63;
  a.wm = a.wave >> 2; a.wn = a.wave & 3;
  a.ln15 = a.ln & 15;
  a.lnoff0 = a.ln15 * 128 + (((a.ln >> 4) * 16) ^ ((a.ln15 & 7) << 4));
  return a;
}
template <int LD>
__device__ __forceinline__ int srcOff256(int wave, int ln) {
  return (wave * 16 + (ln >> 3)) * LD + (((ln & 7) * 8) ^ ((ln >> 3) << 3));
}

// ------------------------------------------- GEMM: Q,K projection (ld=1024)
__global__ __launch_bounds__(512) void gemm_qk256(const ushort* __restrict__ xbf,
                                                  const ushort* __restrict__ WtT,
                                                  const float* __restrict__ bcat,
                                                  ushort* __restrict__ QK) {
  __shared__ __align__(16) char lds[131072];
  int tm = blockIdx.x, tn = blockIdx.y;            // (32, 16)
  Addr256 a = addr256();
  int srcOff = srcOff256<1024>(a.wave, a.ln);
  const ushort* Ap = xbf + (size_t)tm * 256 * 1024;
  const ushort* Bp = WtT + (size_t)tn * 256 * 1024;
  floatx4 acc[8][4];
#pragma unroll
  for (int i = 0; i < 8; ++i)
#pragma unroll
    for (int j = 0; j < 4; ++j) acc[i][j] = (floatx4){0.f, 0.f, 0.f, 0.f};

  prologue256<1024, 1024>(Ap, Bp, lds, a.wave, srcOff, srcOff);
#pragma unroll 1
  for (int i = 0; i < 7; ++i)
    iter256<1024, 1024, false>(Ap, Bp, lds, 2 * i, a.wave, a.wm, a.wn, srcOff, srcOff, a.lnoff0, acc);
  iter256<1024, 1024, true>(Ap, Bp, lds, 14, a.wave, a.wm, a.wn, srcOff, srcOff, a.lnoff0, acc);

  // epilogue: bias + bf16 store; nj innermost -> 4 consecutive stores per line.
  int colb = a.ln15, rowq = (a.ln >> 4) * 4;
  int colbase = tn * 256 + a.wn * 64 + colb;
  float bias[4];
#pragma unroll
  for (int nj = 0; nj < 4; ++nj) bias[nj] = bcat[colbase + nj * 16];
#pragma unroll
  for (int mi = 0; mi < 8; ++mi) {
    int row = tm * 256 + a.wm * 128 + mi * 16 + rowq;
#pragma unroll
    for (int r = 0; r < 4; ++r) {
      ushort* qrow = QK + (size_t)(row + r) * NQK;
#pragma unroll
      for (int nj = 0; nj < 4; ++nj)
        qrow[colbase + nj * 16] = f2bf(acc[mi][nj][r] + bias[nj]);
    }
  }
}

// ------------------------------------------------- GEMM: S = Q*K^T (causal, 256)
__global__ __launch_bounds__(512) void gemm_s256(const ushort* __restrict__ QK,
                                                 float* __restrict__ S) {
  int l = blockIdx.x, b = blockIdx.y;              // l in [0,36)
  int tm = (int)((sqrtf(8.f * l + 1.f) - 1.f) * 0.5f);
  while ((tm + 1) * (tm + 2) / 2 <= l) ++tm;
  while (tm * (tm + 1) / 2 > l) --tm;
  int tn = l - tm * (tm + 1) / 2;
  __shared__ __align__(16) char lds[131072];
  Addr256 a = addr256();
  int srcOff = srcOff256<NQK>(a.wave, a.ln);
  const ushort* Ap = QK + (size_t)b * T_ * NQK + (size_t)tm * 256 * NQK;         // Q rows
  const ushort* Bp = QK + (size_t)b * T_ * NQK + (size_t)tn * 256 * NQK + 2048;  // K rows
  floatx4 acc[8][4];
#pragma unroll
  for (int i = 0; i < 8; ++i)
#pragma unroll
    for (int j = 0; j < 4; ++j) acc[i][j] = (floatx4){0.f, 0.f, 0.f, 0.f};

  prologue256<NQK, NQK>(Ap, Bp, lds, a.wave, srcOff, srcOff);
#pragma unroll 1
  for (int i = 0; i < 15; ++i)
    iter256<NQK, NQK, false>(Ap, Bp, lds, 2 * i, a.wave, a.wm, a.wn, srcOff, srcOff, a.lnoff0, acc);
  iter256<NQK, NQK, true>(Ap, Bp, lds, 30, a.wave, a.wm, a.wn, srcOff, srcOff, a.lnoff0, acc);

  float* Sb = S + (size_t)b * T_ * T_;
  int colb = a.ln15, rowq = (a.ln >> 4) * 4;
  int colbase = tn * 256 + a.wn * 64 + colb;
#pragma unroll
  for (int mi = 0; mi < 8; ++mi) {
    int row = tm * 256 + a.wm * 128 + mi * 16 + rowq;
#pragma unroll
    for (int r = 0; r < 4; ++r) {
      float* srow = Sb + (size_t)(row + r) * T_;
#pragma unroll
      for (int nj = 0; nj < 4; ++nj)
        srow[colbase + nj * 16] = acc[mi][nj][r] * SCALE;
    }
  }
}

// ------------------------------------------------ GEMM: O = P*V (causal, 256)
__global__ __launch_bounds__(512) void gemm_o256(const ushort* __restrict__ P,
                                                 const ushort* __restrict__ Vt,
                                                 float* __restrict__ O) {
  int tn = blockIdx.x, tm = 7 - blockIdx.y, b = blockIdx.z;  // longest-first
  __shared__ __align__(16) char lds[131072];
  Addr256 a = addr256();
  int srcOff = srcOff256<T_>(a.wave, a.ln);
  const ushort* Ap = P + (size_t)b * T_ * T_ + (size_t)tm * 256 * T_;
  const ushort* Bp = Vt + (size_t)b * T_ * T_ + (size_t)tn * 256 * T_;
  floatx4 acc[8][4];
#pragma unroll
  for (int i = 0; i < 8; ++i)
#pragma unroll
    for (int j = 0; j < 4; ++j) acc[i][j] = (floatx4){0.f, 0.f, 0.f, 0.f};

  int niter = (tm + 1) * 2;        // k_end = (tm+1)*256 = niter*128
  prologue256<T_, T_>(Ap, Bp, lds, a.wave, srcOff, srcOff);
#pragma unroll 1
  for (int i = 0; i < niter - 1; ++i)
    iter256<T_, T_, false>(Ap, Bp, lds, 2 * i, a.wave, a.wm, a.wn, srcOff, srcOff, a.lnoff0, acc);
  iter256<T_, T_, true>(Ap, Bp, lds, 2 * (niter - 1), a.wave, a.wm, a.wn, srcOff, srcOff, a.lnoff0, acc);

  float* Ob = O + (size_t)b * T_ * T_;
  int colb = a.ln15, rowq = (a.ln >> 4) * 4;
  int colbase = tn * 256 + a.wn * 64 + colb;
#pragma unroll
  for (int mi = 0; mi < 8; ++mi) {
    int row = tm * 256 + a.wm * 128 + mi * 16 + rowq;
#pragma unroll
    for (int r = 0; r < 4; ++r) {
      float* orow = Ob + (size_t)(row + r) * T_;
#pragma unroll
      for (int nj = 0; nj < 4; ++nj)
        orow[colbase + nj * 16] = acc[mi][nj][r];
    }
  }
}

// --------------------------- GEMM: V projection, writes Vt[b][h][s] directly
__global__ __launch_bounds__(256) void gemm_v(const ushort* __restrict__ xbf,
                                              const ushort* __restrict__ WtT,
                                              const float* __restrict__ bcat,
                                              ushort* __restrict__ Vt) {
  __shared__ __align__(16) char lds[128 * 136 * 2];   // 34816 B; first 16KB = staging
  char* ldsA = lds;
  char* ldsB = lds + 8192;
  int tm = blockIdx.x, tn = blockIdx.y;          // tn in [0,16)
  floatx4 acc[4][4];
#pragma unroll
  for (int i = 0; i < 4; ++i)
#pragma unroll
    for (int j = 0; j < 4; ++j) acc[i][j] = (floatx4){0.f, 0.f, 0.f, 0.f};
  gemm_core(xbf + (size_t)tm * 128 * C_, C_, WtT + (size_t)(32 + tn) * 128 * C_, C_,
            C_ / 32, ldsA, ldsB, acc);
  int tid = threadIdx.x, wave = tid >> 6, lane = tid & 63;
  int wm = wave >> 1, wn = wave & 1;
  int colb = lane & 15, rowq = (lane >> 4) * 4;
  __syncthreads();                               // staging reads all consumed
  ushort* tileT = (ushort*)lds;                  // [h_local][s_local], stride 136
#pragma unroll
  for (int j = 0; j < 4; ++j) {
    int h = wn * 64 + j * 16 + colb;
    float bv = bcat[4096 + tn * 128 + h];
#pragma unroll
    for (int i = 0; i < 4; ++i) {
      int s = wm * 64 + i * 16 + rowq;
      ushort4 o4;
      o4.x = f2bf(acc[i][j][0] + bv);
      o4.y = f2bf(acc[i][j][1] + bv);
      o4.z = f2bf(acc[i][j][2] + bv);
      o4.w = f2bf(acc[i][j][3] + bv);
      *(ushort4*)(tileT + h * 136 + s) = o4;
    }
  }
  __syncthreads();
  int b = tm >> 4, sbase = (tm & 15) * 128;
  int hr = tid >> 4, sc = (tid & 15) * 8;
#pragma unroll
  for (int it = 0; it < 8; ++it) {
    int h = it * 16 + hr;
    ushortx8 v = *(const ushortx8*)(tileT + h * 136 + sc);
    *(ushortx8*)(Vt + ((size_t)b * T_ + tn * 128 + h) * T_ + sbase + sc) = v;
  }
}

// ------------------------------------------------------------ causal softmax
__global__ __launch_bounds__(256) void softmax_causal(const float* __restrict__ S,
                                                      ushort* __restrict__ P) {
  int t = blockIdx.x, b = blockIdx.y;
  int tid = threadIdx.x;
  const float* srow = S + ((size_t)b * T_ + t) * T_;
  ushort* prow = P + ((size_t)b * T_ + t) * T_;
  int band = ((t >> 8) + 1) << 8;    // round_up(t+1, 256) == gemm_o256 k_end
  float xv[8];
  float m = -INFINITY;
#pragma unroll
  for (int c = 0; c < 2; ++c) {
    int s0 = c * 1024 + tid * 4;
    float* xs = xv + c * 4;
    if (s0 < band) {
      float4 v = *(const float4*)(srow + s0);
      xs[0] = (s0 + 0 <= t) ? v.x : -INFINITY;  // scale applied in gemm_s
      xs[1] = (s0 + 1 <= t) ? v.y : -INFINITY;
      xs[2] = (s0 + 2 <= t) ? v.z : -INFINITY;
      xs[3] = (s0 + 3 <= t) ? v.w : -INFINITY;
      m = fmaxf(fmaxf(fmaxf(xs[0], xs[1]), fmaxf(xs[2], xs[3])), m);
    } else {
      xs[0] = xs[1] = xs[2] = xs[3] = -INFINITY;
    }
  }
  __shared__ float sm4[4];
  int wid = tid >> 6, ln = tid & 63;
#pragma unroll
  for (int o = 32; o; o >>= 1) m = fmaxf(m, __shfl_xor(m, o));
  if (ln == 0) sm4[wid] = m;
  __syncthreads();
  m = fmaxf(fmaxf(sm4[0], sm4[1]), fmaxf(sm4[2], sm4[3]));
  __syncthreads();
  float sum = 0.f;
#pragma unroll
  for (int k = 0; k < 8; ++k) { xv[k] = __expf(xv[k] - m); sum += xv[k]; }
#pragma unroll
  for (int o = 32; o; o >>= 1) sum += __shfl_xor(sum, o);
  if (ln == 0) sm4[wid] = sum;
  __syncthreads();
  sum = sm4[0] + sm4[1] + sm4[2] + sm4[3];
  float inv = 1.0f / sum;
#pragma unroll
  for (int c = 0; c < 2; ++c) {
    int s0 = c * 1024 + tid * 4;
    if (s0 < band) {
      ushort4 o4;
      o4.x = f2bf(xv[c * 4 + 0] * inv);
      o4.y = f2bf(xv[c * 4 + 1] * inv);
      o4.z = f2bf(xv[c * 4 + 2] * inv);
      o4.w = f2bf(xv[c * 4 + 3] * inv);
      *(ushort4*)(prow + s0) = o4;
    }
  }
}

// ---------------------------------------------------------------- launcher
extern "C" void kernel_launch(void* const* d_in, const int* in_sizes, int n_in,
                              void* d_out, int out_size, void* d_ws, size_t ws_size,
                              hipStream_t stream) {
  (void)in_sizes; (void)n_in; (void)out_size; (void)ws_size;
  const float* x  = (const float*)d_in[0];
  const float* Wq = (const float*)d_in[1];
  const float* bq = (const float*)d_in[2];
  const float* Wk = (const float*)d_in[3];
  const float* bk = (const float*)d_in[4];
  const float* Wv = (const float*)d_in[5];
  const float* bv = (const float*)d_in[6];

  char* ws = (char*)d_ws;
  ushort* xbf  = (ushort*)(ws + 0);           // 16,777,216 B
  ushort* WtT  = (ushort*)(ws + 16777216);    // 12,582,912 B
  float*  bcat = (float*) (ws + 29360128);    //     24,576 B
  ushort* QK   = (ushort*)(ws + 29384704);    // 67,108,864 B  [8192][4096]
  ushort* P    = (ushort*)(ws + 96493568);    // 33,554,432 B
  ushort* Vt   = (ushort*)(ws + 130048000);   // 33,554,432 B  (end ~156 MiB)

  float* S = (float*)d_out;   // S scratch lives in d_out, later overwritten by O
  float* O = (float*)d_out;

  cast_x_kernel  <<<8192, 256, 0, stream>>>(x, xbf);
  wcast_t_kernel <<<dim3(32, 192), dim3(32, 8), 0, stream>>>(Wq, Wk, Wv, WtT);
  bias_cat_kernel<<<24, 256, 0, stream>>>(bq, bk, bv, bcat);
  gemm_qk256     <<<dim3(32, 16), 512, 0, stream>>>(xbf, WtT, bcat, QK);
  gemm_v         <<<dim3(64, 16), 256, 0, stream>>>(xbf, WtT, bcat, Vt);
  gemm_s256      <<<dim3(36, 4), 512, 0, stream>>>(QK, S);
  softmax_causal <<<dim3(2048, 4), 256, 0, stream>>>(S, P);
  gemm_o256      <<<dim3(8, 8, 4), 512, 0, stream>>>(P, Vt, O);
}

// Round 4
// 349.631 us; speedup vs baseline: 1.2510x; 1.0296x over previous
//
#include <hip/hip_runtime.h>

// AttentionHead  B=4, T=2048, C=1024, HEAD=2048, fp32 in/out.
// Round 7: the r6 8-phase core was phase-serial ([LDS reads]->bar->lgkm0->
// [MFMA]->bar with sched_barrier(0) pinning everywhere) so LDS service and
// MFMA never overlap -> MfmaUtil 39%. Restructure into 4 phase-PAIRS per
// iter: one s_barrier per pair, no manual lgkmcnt, no intra-pair
// sched_barriers -> compiler interleaves ds_read issue into the MFMA shadow
// (m97-style). vmcnt gates re-derived at pair granularity (pair-B end: buf1
// ready; pair-D end: buf0 ready). Hazards: every stage target's last reads
// complete >=1 barrier earlier (reads are consumed by MFMA within the pair).

#define T_    2048
#define C_    1024
#define B_    4
#define NQK   4096
#define SCALE 0.03125f   // C^-0.5 = 1/32 exactly

typedef __attribute__((ext_vector_type(4))) float floatx4;
typedef __attribute__((ext_vector_type(8))) short short8;
typedef __attribute__((ext_vector_type(8))) unsigned short ushortx8;

__device__ __forceinline__ unsigned short f2bf(float f) {
  unsigned int u = __float_as_uint(f);
  unsigned int r = (u + 0x7fffu + ((u >> 16) & 1u)) >> 16;  // RNE
  return (unsigned short)r;
}

// ---------------------------------------------------------------- cast x
__global__ void cast_x_kernel(const float* __restrict__ x, ushort* __restrict__ xbf) {
  int i = blockIdx.x * 256 + threadIdx.x;          // over N/4 = 2097152
  float4 v = ((const float4*)x)[i];
  ushort4 o;
  o.x = f2bf(v.x); o.y = f2bf(v.y); o.z = f2bf(v.z); o.w = f2bf(v.w);
  ((ushort4*)xbf)[i] = o;
}

// ------------------------------------------- cast + transpose W -> WtT[n][k]
__global__ void wcast_t_kernel(const float* __restrict__ Wq, const float* __restrict__ Wk,
                               const float* __restrict__ Wv, ushort* __restrict__ WtT) {
  int k0 = blockIdx.x * 32;           // over C=1024
  int n0 = blockIdx.y * 32;           // over 6144
  const float* W = (n0 < 2048) ? Wq : (n0 < 4096 ? Wk : Wv);
  int nl0 = n0 & 2047;
  __shared__ ushort tile[32][33];
  int tx = threadIdx.x, ty = threadIdx.y;
  for (int r = ty; r < 32; r += 8)
    tile[r][tx] = f2bf(W[(size_t)(k0 + r) * 2048 + nl0 + tx]);
  __syncthreads();
  for (int r = ty; r < 32; r += 8)
    WtT[(size_t)(n0 + r) * 1024 + k0 + tx] = tile[tx][r];
}

// ---------------------------------------------------------------- bias concat
__global__ void bias_cat_kernel(const float* __restrict__ bq, const float* __restrict__ bk,
                                const float* __restrict__ bv, float* __restrict__ bcat) {
  int i = blockIdx.x * 256 + threadIdx.x;
  if (i < 6144) {
    const float* s = (i < 2048) ? bq : (i < 4096 ? bk : bv);
    bcat[i] = s[i & 2047];
  }
}

// ------------------------------------------------------- GEMM core (m97 BT)
__device__ __forceinline__ void stage128x32(const ushort* g, int ld, char* lds,
                                            int wave, int lane) {
#pragma unroll
  for (int c = 0; c < 2; ++c) {
    int chunk = wave + 4 * c;                       // 8 chunks of 16 rows
    const ushort* gaddr = g + (size_t)(chunk * 16 + (lane >> 2)) * ld + (lane & 3) * 8;
    char* laddr = lds + chunk * 1024;               // wave-uniform
    __builtin_amdgcn_global_load_lds((const __attribute__((address_space(1))) unsigned int*)gaddr,
                                     (__attribute__((address_space(3))) unsigned int*)laddr,
                                     16, 0, 0);
  }
}

__device__ __forceinline__ void gemm_core(const ushort* A, int lda,
                                          const ushort* Bm, int ldb, int ksteps,
                                          char* ldsA, char* ldsB, floatx4 acc[4][4]) {
  int tid = threadIdx.x;
  int wave = tid >> 6, lane = tid & 63;
  int wm = wave >> 1, wn = wave & 1;
  int koff2 = ((lane >> 4) * 8) * 2;   // byte offset of k-fragment
  int rbase = lane & 15;
  for (int s = 0; s < ksteps; ++s) {
    __syncthreads();                              // LDS reads of prev iter done
    stage128x32(A + s * 32, lda, ldsA, wave, lane);
    stage128x32(Bm + s * 32, ldb, ldsB, wave, lane);
    __syncthreads();                              // vmcnt drain before reads
    short8 af[4], bf[4];
#pragma unroll
    for (int i = 0; i < 4; ++i) {
      af[i] = *(const short8*)(ldsA + (wm * 64 + i * 16 + rbase) * 64 + koff2);
      bf[i] = *(const short8*)(ldsB + (wn * 64 + i * 16 + rbase) * 64 + koff2);
    }
#pragma unroll
    for (int i = 0; i < 4; ++i)
#pragma unroll
      for (int j = 0; j < 4; ++j)
        acc[i][j] = __builtin_amdgcn_mfma_f32_16x16x32_bf16(af[i], bf[j], acc[i][j], 0, 0, 0);
  }
}

// ===================== 256x256 pair-pipelined GEMM core (BT, bf16) ==============
// Geometry: BM=BN=256, BK=64, 8 waves (wm=wave>>2, wn=wave&3), per-wave output
// 128x64 (acc[8][4] of 16x16 frags). LDS 128 KiB:
//   A: buf0 @0,16384; buf1 @32768,49152   (region = 128 rows x 64 cols bf16)
//   B: buf0 @65536,81920; buf1 @98304,114688
// Swizzle: physical byte-in-row = logical ^ ((row&7)<<4) (conflict-free, r5).
// Pair schedule per iter (tiles t=buf0, t+1=buf1), one s_barrier per pair:
//   pairA: read A-lo(t)+B(all,t), stage (t+1,A)->buf1A,  32 MFMA (m-lo)
//   pairB: read A-hi(t),          stage (t+2,B)->buf0B,  32 MFMA (m-hi)
//          gate vmcnt(4) [buf1A + prev buf1B confirmed]
//   pairC: read A-lo(t+1)+B(t+1), stage (t+2,A)->buf0A,  32 MFMA (m-lo)
//   pairD: read A-hi(t+1),        stage (t+3,B)->buf1B,  32 MFMA (m-hi)
//          gate vmcnt(4) [all buf0 for next iter confirmed]
// No manual lgkmcnt: compiler inserts minimal counted waits and interleaves
// ds_read issue with MFMA. sched_barrier(0) only flanks s_barrier / vmcnt.

#define MFMA16(a, b, c) __builtin_amdgcn_mfma_f32_16x16x32_bf16((a), (b), (c), 0, 0, 0)

#define GLDS16(gsrc, ldst)                                                                       \
  __builtin_amdgcn_global_load_lds((const __attribute__((address_space(1))) unsigned int*)(gsrc), \
                                   (__attribute__((address_space(3))) unsigned int*)(ldst), 16, 0, 0)

template <int LD>
__device__ __forceinline__ void stage_half(const ushort* gsrc, char* ldst) {
  GLDS16(gsrc, ldst);
  GLDS16(gsrc + 8 * LD, ldst + 1024);
}

#define BARX() do {                                        \
  __builtin_amdgcn_sched_barrier(0);                       \
  __builtin_amdgcn_s_barrier();                            \
  __builtin_amdgcn_sched_barrier(0);                       \
} while (0)

template <int LDA, int LDB>
__device__ __forceinline__ void prologue256(const ushort* Ap, const ushort* Bp,
                                            char* lds, int wave, int srcOffA, int srcOffB) {
  stage_half<LDA>(Ap + srcOffA,                     lds + wave * 2048);
  stage_half<LDA>(Ap + 128 * LDA + srcOffA,         lds + 16384 + wave * 2048);
  stage_half<LDB>(Bp + srcOffB,                     lds + 65536 + wave * 2048);
  stage_half<LDB>(Bp + 128 * LDB + srcOffB,         lds + 81920 + wave * 2048);
  stage_half<LDB>(Bp + 64 + srcOffB,                lds + 98304 + wave * 2048);
  stage_half<LDB>(Bp + 64 + 128 * LDB + srcOffB,    lds + 114688 + wave * 2048);
  __builtin_amdgcn_sched_barrier(0);
  asm volatile("s_waitcnt vmcnt(4)" ::: "memory");
  BARX();
}

template <int LDA, int LDB, bool TAIL>
__device__ __forceinline__ void iter256(const ushort* __restrict__ Ap,
                                        const ushort* __restrict__ Bp,
                                        char* lds, int kt0, int wave, int wm, int wn,
                                        int srcOffA, int srcOffB, int lnoff0,
                                        floatx4 (&acc)[8][4]) {
  char* rA0 = lds + wm * 16384;                    // tile kt0   (buf0) A, this wave
  char* rA1 = rA0 + 32768;                         // tile kt0+1 (buf1) A
  char* rB0 = lds + 65536 + (wn >> 1) * 16384 + (wn & 1) * 8192;
  char* rB1 = rB0 + 32768;
  const ushort* sA1 = Ap + (kt0 + 1) * 64 + srcOffA;
  const ushort* sA2 = Ap + (kt0 + 2) * 64 + srcOffA;
  const ushort* sB2 = Bp + (kt0 + 2) * 64 + srcOffB;
  const ushort* sB3 = Bp + (kt0 + 3) * 64 + srcOffB;
  const int lnoff1 = lnoff0 ^ 64;                  // second k-frag (swz carries bit6)
  short8 af[4][2], b4[4][2];

  // ==== pair A: tile kt0, m-lo rows x all n ============================
#pragma unroll
  for (int mi = 0; mi < 4; ++mi) {
    af[mi][0] = *(const short8*)(rA0 + mi * 2048 + lnoff0);
    af[mi][1] = *(const short8*)(rA0 + mi * 2048 + lnoff1);
  }
#pragma unroll
  for (int nj = 0; nj < 4; ++nj) {
    b4[nj][0] = *(const short8*)(rB0 + nj * 2048 + lnoff0);
    b4[nj][1] = *(const short8*)(rB0 + nj * 2048 + lnoff1);
  }
  stage_half<LDA>(sA1, lds + 32768 + wave * 2048);
  stage_half<LDA>(sA1 + 128 * LDA, lds + 49152 + wave * 2048);
  __builtin_amdgcn_s_setprio(1);
#pragma unroll
  for (int mi = 0; mi < 4; ++mi)
#pragma unroll
    for (int nj = 0; nj < 4; ++nj) {
      acc[mi][nj] = MFMA16(af[mi][0], b4[nj][0], acc[mi][nj]);
      acc[mi][nj] = MFMA16(af[mi][1], b4[nj][1], acc[mi][nj]);
    }
  __builtin_amdgcn_s_setprio(0);
  BARX();

  // ==== pair B: tile kt0, m-hi rows ====================================
#pragma unroll
  for (int mi = 0; mi < 4; ++mi) {
    af[mi][0] = *(const short8*)(rA0 + (4 + mi) * 2048 + lnoff0);
    af[mi][1] = *(const short8*)(rA0 + (4 + mi) * 2048 + lnoff1);
  }
  if constexpr (!TAIL) {
    stage_half<LDB>(sB2, lds + 65536 + wave * 2048);
    stage_half<LDB>(sB2 + 128 * LDB, lds + 81920 + wave * 2048);
  }
  __builtin_amdgcn_s_setprio(1);
#pragma unroll
  for (int mi = 0; mi < 4; ++mi)
#pragma unroll
    for (int nj = 0; nj < 4; ++nj) {
      acc[4 + mi][nj] = MFMA16(af[mi][0], b4[nj][0], acc[4 + mi][nj]);
      acc[4 + mi][nj] = MFMA16(af[mi][1], b4[nj][1], acc[4 + mi][nj]);
    }
  __builtin_amdgcn_s_setprio(0);
  __builtin_amdgcn_sched_barrier(0);
  if constexpr (TAIL) asm volatile("s_waitcnt vmcnt(0)" ::: "memory");
  else                asm volatile("s_waitcnt vmcnt(4)" ::: "memory");
  BARX();

  // ==== pair C: tile kt0+1, m-lo rows x all n ==========================
#pragma unroll
  for (int mi = 0; mi < 4; ++mi) {
    af[mi][0] = *(const short8*)(rA1 + mi * 2048 + lnoff0);
    af[mi][1] = *(const short8*)(rA1 + mi * 2048 + lnoff1);
  }
#pragma unroll
  for (int nj = 0; nj < 4; ++nj) {
    b4[nj][0] = *(const short8*)(rB1 + nj * 2048 + lnoff0);
    b4[nj][1] = *(const short8*)(rB1 + nj * 2048 + lnoff1);
  }
  if constexpr (!TAIL) {
    stage_half<LDA>(sA2, lds + wave * 2048);
    stage_half<LDA>(sA2 + 128 * LDA, lds + 16384 + wave * 2048);
  }
  __builtin_amdgcn_s_setprio(1);
#pragma unroll
  for (int mi = 0; mi < 4; ++mi)
#pragma unroll
    for (int nj = 0; nj < 4; ++nj) {
      acc[mi][nj] = MFMA16(af[mi][0], b4[nj][0], acc[mi][nj]);
      acc[mi][nj] = MFMA16(af[mi][1], b4[nj][1], acc[mi][nj]);
    }
  __builtin_amdgcn_s_setprio(0);
  BARX();

  // ==== pair D: tile kt0+1, m-hi rows ==================================
#pragma unroll
  for (int mi = 0; mi < 4; ++mi) {
    af[mi][0] = *(const short8*)(rA1 + (4 + mi) * 2048 + lnoff0);
    af[mi][1] = *(const short8*)(rA1 + (4 + mi) * 2048 + lnoff1);
  }
  if constexpr (!TAIL) {
    stage_half<LDB>(sB3, lds + 98304 + wave * 2048);
    stage_half<LDB>(sB3 + 128 * LDB, lds + 114688 + wave * 2048);
  }
  __builtin_amdgcn_s_setprio(1);
#pragma unroll
  for (int mi = 0; mi < 4; ++mi)
#pragma unroll
    for (int nj = 0; nj < 4; ++nj) {
      acc[4 + mi][nj] = MFMA16(af[mi][0], b4[nj][0], acc[4 + mi][nj]);
      acc[4 + mi][nj] = MFMA16(af[mi][1], b4[nj][1], acc[4 + mi][nj]);
    }
  __builtin_amdgcn_s_setprio(0);
  __builtin_amdgcn_sched_barrier(0);
  if constexpr (!TAIL) asm volatile("s_waitcnt vmcnt(4)" ::: "memory");
  BARX();
}

// Per-thread addressing for the 256x256 core.
struct Addr256 {
  int wave, wm, wn, ln, ln15, lnoff0;
};
__device__ __forceinline__ Addr256 addr256() {
  Addr256 a;
  int tid = threadIdx.x;
  a.wave = tid >> 6; a.ln = tid & 63;
  a.wm = a.wave >> 2; a.wn = a.wave & 3;
  a.ln15 = a.ln & 15;
  a.lnoff0 = a.ln15 * 128 + (((a.ln >> 4) * 16) ^ ((a.ln15 & 7) << 4));
  return a;
}
template <int LD>
__device__ __forceinline__ int srcOff256(int wave, int ln) {
  return (wave * 16 + (ln >> 3)) * LD + (((ln & 7) * 8) ^ ((ln >> 3) << 3));
}

// ------------------------------------------- GEMM: Q,K projection (ld=1024)
__global__ __launch_bounds__(512) void gemm_qk256(const ushort* __restrict__ xbf,
                                                  const ushort* __restrict__ WtT,
                                                  const float* __restrict__ bcat,
                                                  ushort* __restrict__ QK) {
  __shared__ __align__(16) char lds[131072];
  int tm = blockIdx.x, tn = blockIdx.y;            // (32, 16)
  Addr256 a = addr256();
  int srcOff = srcOff256<1024>(a.wave, a.ln);
  const ushort* Ap = xbf + (size_t)tm * 256 * 1024;
  const ushort* Bp = WtT + (size_t)tn * 256 * 1024;
  floatx4 acc[8][4];
#pragma unroll
  for (int i = 0; i < 8; ++i)
#pragma unroll
    for (int j = 0; j < 4; ++j) acc[i][j] = (floatx4){0.f, 0.f, 0.f, 0.f};

  prologue256<1024, 1024>(Ap, Bp, lds, a.wave, srcOff, srcOff);
#pragma unroll 1
  for (int i = 0; i < 7; ++i)
    iter256<1024, 1024, false>(Ap, Bp, lds, 2 * i, a.wave, a.wm, a.wn, srcOff, srcOff, a.lnoff0, acc);
  iter256<1024, 1024, true>(Ap, Bp, lds, 14, a.wave, a.wm, a.wn, srcOff, srcOff, a.lnoff0, acc);

  // epilogue: bias + bf16 store; nj innermost -> 4 consecutive stores per line.
  int colb = a.ln15, rowq = (a.ln >> 4) * 4;
  int colbase = tn * 256 + a.wn * 64 + colb;
  float bias[4];
#pragma unroll
  for (int nj = 0; nj < 4; ++nj) bias[nj] = bcat[colbase + nj * 16];
#pragma unroll
  for (int mi = 0; mi < 8; ++mi) {
    int row = tm * 256 + a.wm * 128 + mi * 16 + rowq;
#pragma unroll
    for (int r = 0; r < 4; ++r) {
      ushort* qrow = QK + (size_t)(row + r) * NQK;
#pragma unroll
      for (int nj = 0; nj < 4; ++nj)
        qrow[colbase + nj * 16] = f2bf(acc[mi][nj][r] + bias[nj]);
    }
  }
}

// ------------------------------------------------- GEMM: S = Q*K^T (causal, 256)
__global__ __launch_bounds__(512) void gemm_s256(const ushort* __restrict__ QK,
                                                 float* __restrict__ S) {
  int l = blockIdx.x, b = blockIdx.y;              // l in [0,36)
  int tm = (int)((sqrtf(8.f * l + 1.f) - 1.f) * 0.5f);
  while ((tm + 1) * (tm + 2) / 2 <= l) ++tm;
  while (tm * (tm + 1) / 2 > l) --tm;
  int tn = l - tm * (tm + 1) / 2;
  __shared__ __align__(16) char lds[131072];
  Addr256 a = addr256();
  int srcOff = srcOff256<NQK>(a.wave, a.ln);
  const ushort* Ap = QK + (size_t)b * T_ * NQK + (size_t)tm * 256 * NQK;         // Q rows
  const ushort* Bp = QK + (size_t)b * T_ * NQK + (size_t)tn * 256 * NQK + 2048;  // K rows
  floatx4 acc[8][4];
#pragma unroll
  for (int i = 0; i < 8; ++i)
#pragma unroll
    for (int j = 0; j < 4; ++j) acc[i][j] = (floatx4){0.f, 0.f, 0.f, 0.f};

  prologue256<NQK, NQK>(Ap, Bp, lds, a.wave, srcOff, srcOff);
#pragma unroll 1
  for (int i = 0; i < 15; ++i)
    iter256<NQK, NQK, false>(Ap, Bp, lds, 2 * i, a.wave, a.wm, a.wn, srcOff, srcOff, a.lnoff0, acc);
  iter256<NQK, NQK, true>(Ap, Bp, lds, 30, a.wave, a.wm, a.wn, srcOff, srcOff, a.lnoff0, acc);

  float* Sb = S + (size_t)b * T_ * T_;
  int colb = a.ln15, rowq = (a.ln >> 4) * 4;
  int colbase = tn * 256 + a.wn * 64 + colb;
#pragma unroll
  for (int mi = 0; mi < 8; ++mi) {
    int row = tm * 256 + a.wm * 128 + mi * 16 + rowq;
#pragma unroll
    for (int r = 0; r < 4; ++r) {
      float* srow = Sb + (size_t)(row + r) * T_;
#pragma unroll
      for (int nj = 0; nj < 4; ++nj)
        srow[colbase + nj * 16] = acc[mi][nj][r] * SCALE;
    }
  }
}

// ------------------------------------------------ GEMM: O = P*V (causal, 256)
__global__ __launch_bounds__(512) void gemm_o256(const ushort* __restrict__ P,
                                                 const ushort* __restrict__ Vt,
                                                 float* __restrict__ O) {
  int tn = blockIdx.x, tm = 7 - blockIdx.y, b = blockIdx.z;  // longest-first
  __shared__ __align__(16) char lds[131072];
  Addr256 a = addr256();
  int srcOff = srcOff256<T_>(a.wave, a.ln);
  const ushort* Ap = P + (size_t)b * T_ * T_ + (size_t)tm * 256 * T_;
  const ushort* Bp = Vt + (size_t)b * T_ * T_ + (size_t)tn * 256 * T_;
  floatx4 acc[8][4];
#pragma unroll
  for (int i = 0; i < 8; ++i)
#pragma unroll
    for (int j = 0; j < 4; ++j) acc[i][j] = (floatx4){0.f, 0.f, 0.f, 0.f};

  int niter = (tm + 1) * 2;        // k_end = (tm+1)*256 = niter*128
  prologue256<T_, T_>(Ap, Bp, lds, a.wave, srcOff, srcOff);
#pragma unroll 1
  for (int i = 0; i < niter - 1; ++i)
    iter256<T_, T_, false>(Ap, Bp, lds, 2 * i, a.wave, a.wm, a.wn, srcOff, srcOff, a.lnoff0, acc);
  iter256<T_, T_, true>(Ap, Bp, lds, 2 * (niter - 1), a.wave, a.wm, a.wn, srcOff, srcOff, a.lnoff0, acc);

  float* Ob = O + (size_t)b * T_ * T_;
  int colb = a.ln15, rowq = (a.ln >> 4) * 4;
  int colbase = tn * 256 + a.wn * 64 + colb;
#pragma unroll
  for (int mi = 0; mi < 8; ++mi) {
    int row = tm * 256 + a.wm * 128 + mi * 16 + rowq;
#pragma unroll
    for (int r = 0; r < 4; ++r) {
      float* orow = Ob + (size_t)(row + r) * T_;
#pragma unroll
      for (int nj = 0; nj < 4; ++nj)
        orow[colbase + nj * 16] = acc[mi][nj][r];
    }
  }
}

// --------------------------- GEMM: V projection, writes Vt[b][h][s] directly
__global__ __launch_bounds__(256) void gemm_v(const ushort* __restrict__ xbf,
                                              const ushort* __restrict__ WtT,
                                              const float* __restrict__ bcat,
                                              ushort* __restrict__ Vt) {
  __shared__ __align__(16) char lds[128 * 136 * 2];   // 34816 B; first 16KB = staging
  char* ldsA = lds;
  char* ldsB = lds + 8192;
  int tm = blockIdx.x, tn = blockIdx.y;          // tn in [0,16)
  floatx4 acc[4][4];
#pragma unroll
  for (int i = 0; i < 4; ++i)
#pragma unroll
    for (int j = 0; j < 4; ++j) acc[i][j] = (floatx4){0.f, 0.f, 0.f, 0.f};
  gemm_core(xbf + (size_t)tm * 128 * C_, C_, WtT + (size_t)(32 + tn) * 128 * C_, C_,
            C_ / 32, ldsA, ldsB, acc);
  int tid = threadIdx.x, wave = tid >> 6, lane = tid & 63;
  int wm = wave >> 1, wn = wave & 1;
  int colb = lane & 15, rowq = (lane >> 4) * 4;
  __syncthreads();                               // staging reads all consumed
  ushort* tileT = (ushort*)lds;                  // [h_local][s_local], stride 136
#pragma unroll
  for (int j = 0; j < 4; ++j) {
    int h = wn * 64 + j * 16 + colb;
    float bv = bcat[4096 + tn * 128 + h];
#pragma unroll
    for (int i = 0; i < 4; ++i) {
      int s = wm * 64 + i * 16 + rowq;
      ushort4 o4;
      o4.x = f2bf(acc[i][j][0] + bv);
      o4.y = f2bf(acc[i][j][1] + bv);
      o4.z = f2bf(acc[i][j][2] + bv);
      o4.w = f2bf(acc[i][j][3] + bv);
      *(ushort4*)(tileT + h * 136 + s) = o4;
    }
  }
  __syncthreads();
  int b = tm >> 4, sbase = (tm & 15) * 128;
  int hr = tid >> 4, sc = (tid & 15) * 8;
#pragma unroll
  for (int it = 0; it < 8; ++it) {
    int h = it * 16 + hr;
    ushortx8 v = *(const ushortx8*)(tileT + h * 136 + sc);
    *(ushortx8*)(Vt + ((size_t)b * T_ + tn * 128 + h) * T_ + sbase + sc) = v;
  }
}

// ------------------------------------------------------------ causal softmax
__global__ __launch_bounds__(256) void softmax_causal(const float* __restrict__ S,
                                                      ushort* __restrict__ P) {
  int t = blockIdx.x, b = blockIdx.y;
  int tid = threadIdx.x;
  const float* srow = S + ((size_t)b * T_ + t) * T_;
  ushort* prow = P + ((size_t)b * T_ + t) * T_;
  int band = ((t >> 8) + 1) << 8;    // round_up(t+1, 256) == gemm_o256 k_end
  float xv[8];
  float m = -INFINITY;
#pragma unroll
  for (int c = 0; c < 2; ++c) {
    int s0 = c * 1024 + tid * 4;
    float* xs = xv + c * 4;
    if (s0 < band) {
      float4 v = *(const float4*)(srow + s0);
      xs[0] = (s0 + 0 <= t) ? v.x : -INFINITY;  // scale applied in gemm_s
      xs[1] = (s0 + 1 <= t) ? v.y : -INFINITY;
      xs[2] = (s0 + 2 <= t) ? v.z : -INFINITY;
      xs[3] = (s0 + 3 <= t) ? v.w : -INFINITY;
      m = fmaxf(fmaxf(fmaxf(xs[0], xs[1]), fmaxf(xs[2], xs[3])), m);
    } else {
      xs[0] = xs[1] = xs[2] = xs[3] = -INFINITY;
    }
  }
  __shared__ float sm4[4];
  int wid = tid >> 6, ln = tid & 63;
#pragma unroll
  for (int o = 32; o; o >>= 1) m = fmaxf(m, __shfl_xor(m, o));
  if (ln == 0) sm4[wid] = m;
  __syncthreads();
  m = fmaxf(fmaxf(sm4[0], sm4[1]), fmaxf(sm4[2], sm4[3]));
  __syncthreads();
  float sum = 0.f;
#pragma unroll
  for (int k = 0; k < 8; ++k) { xv[k] = __expf(xv[k] - m); sum += xv[k]; }
#pragma unroll
  for (int o = 32; o; o >>= 1) sum += __shfl_xor(sum, o);
  if (ln == 0) sm4[wid] = sum;
  __syncthreads();
  sum = sm4[0] + sm4[1] + sm4[2] + sm4[3];
  float inv = 1.0f / sum;
#pragma unroll
  for (int c = 0; c < 2; ++c) {
    int s0 = c * 1024 + tid * 4;
    if (s0 < band) {
      ushort4 o4;
      o4.x = f2bf(xv[c * 4 + 0] * inv);
      o4.y = f2bf(xv[c * 4 + 1] * inv);
      o4.z = f2bf(xv[c * 4 + 2] * inv);
      o4.w = f2bf(xv[c * 4 + 3] * inv);
      *(ushort4*)(prow + s0) = o4;
    }
  }
}

// ---------------------------------------------------------------- launcher
extern "C" void kernel_launch(void* const* d_in, const int* in_sizes, int n_in,
                              void* d_out, int out_size, void* d_ws, size_t ws_size,
                              hipStream_t stream) {
  (void)in_sizes; (void)n_in; (void)out_size; (void)ws_size;
  const float* x  = (const float*)d_in[0];
  const float* Wq = (const float*)d_in[1];
  const float* bq = (const float*)d_in[2];
  const float* Wk = (const float*)d_in[3];
  const float* bk = (const float*)d_in[4];
  const float* Wv = (const float*)d_in[5];
  const float* bv = (const float*)d_in[6];

  char* ws = (char*)d_ws;
  ushort* xbf  = (ushort*)(ws + 0);           // 16,777,216 B
  ushort* WtT  = (ushort*)(ws + 16777216);    // 12,582,912 B
  float*  bcat = (float*) (ws + 29360128);    //     24,576 B
  ushort* QK   = (ushort*)(ws + 29384704);    // 67,108,864 B  [8192][4096]
  ushort* P    = (ushort*)(ws + 96493568);    // 33,554,432 B
  ushort* Vt   = (ushort*)(ws + 130048000);   // 33,554,432 B  (end ~156 MiB)

  float* S = (float*)d_out;   // S scratch lives in d_out, later overwritten by O
  float* O = (float*)d_out;

  cast_x_kernel  <<<8192, 256, 0, stream>>>(x, xbf);
  wcast_t_kernel <<<dim3(32, 192), dim3(32, 8), 0, stream>>>(Wq, Wk, Wv, WtT);
  bias_cat_kernel<<<24, 256, 0, stream>>>(bq, bk, bv, bcat);
  gemm_qk256     <<<dim3(32, 16), 512, 0, stream>>>(xbf, WtT, bcat, QK);
  gemm_v         <<<dim3(64, 16), 256, 0, stream>>>(xbf, WtT, bcat, Vt);
  gemm_s256      <<<dim3(36, 4), 512, 0, stream>>>(QK, S);
  softmax_causal <<<dim3(2048, 4), 256, 0, stream>>>(S, P);
  gemm_o256      <<<dim3(8, 8, 4), 512, 0, stream>>>(P, Vt, O);
}